// Round 11
// baseline (634.096 us; speedup 1.0000x reference)
//
#include <hip/hip_runtime.h>
#include <cstdint>
#include <cmath>

#define NB 4
#define NQn 128
#define QD 512
#define EMBD 512
#define NH 8
#define DHn 64
#define VOCAB 20000
#define WDn 300
#define VCHUNK 128
#define NCHUNK 157   // ceil(20000/128)

typedef float f32x4 __attribute__((ext_vector_type(4)));
typedef float f32x2 __attribute__((ext_vector_type(2)));

__device__ __forceinline__ f32x2 lo2(f32x4 v) { return __builtin_shufflevector(v, v, 0, 1); }
__device__ __forceinline__ f32x2 hi2(f32x4 v) { return __builtin_shufflevector(v, v, 2, 3); }

__device__ __forceinline__ void pk_fma(f32x2 &d, f32x2 a, f32x2 b) {
  asm("v_pk_fma_f32 %0, %1, %2, %0" : "+v"(d) : "v"(a), "v"(b));
}
__device__ __forceinline__ void pk_fma_blo(f32x2 &d, f32x2 a, f32x2 b) {
  asm("v_pk_fma_f32 %0, %1, %2, %0 op_sel:[0,0,0] op_sel_hi:[0,1,1]"
      : "+v"(d) : "v"(a), "v"(b));
}
__device__ __forceinline__ void pk_fma_bhi(f32x2 &d, f32x2 a, f32x2 b) {
  asm("v_pk_fma_f32 %0, %1, %2, %0 op_sel:[1,0,0] op_sel_hi:[1,1,1]"
      : "+v"(d) : "v"(a), "v"(b));
}

__device__ __forceinline__ uint32_t rotl(uint32_t x, int r) {
  return __builtin_amdgcn_alignbit(x, x, 32 - r);
}

// 8 interleaved threefry2x32 chains (key=(0,42)); bits = out0 ^ out1 (verified R1)
#define TFK1 42u
#define TFK2 (0x1BD11BDAu ^ 42u)
__device__ __forceinline__ void tf8(uint32_t (&x0)[8], uint32_t (&x1)[8]) {
#define R8(r) \
  { _Pragma("unroll") for (int j = 0; j < 8; ++j) { x0[j] += x1[j]; x1[j] = rotl(x1[j], r); x1[j] ^= x0[j]; } }
#define K8(a, b) \
  { _Pragma("unroll") for (int j = 0; j < 8; ++j) { x0[j] += (a); x1[j] += (b); } }
  K8(0u, TFK1)
  R8(13) R8(15) R8(26) R8(6)  K8(TFK1, TFK2 + 1u)
  R8(17) R8(29) R8(16) R8(24) K8(TFK2, 0u + 2u)
  R8(13) R8(15) R8(26) R8(6)  K8(0u, TFK1 + 3u)
  R8(17) R8(29) R8(16) R8(24) K8(TFK1, TFK2 + 4u)
  R8(13) R8(15) R8(26) R8(6)  K8(TFK2, 0u + 5u)
#undef R8
#undef K8
}

__device__ __forceinline__ float gumbel_from_bits(uint32_t bits) {
  float f = __uint_as_float((bits >> 9) | 0x3f800000u) - 1.0f;
  float u = fmaxf(f, 1.17549435e-38f);
  float t = __log2f(u);
  float s = __log2f(-t);
  return fmaf(0.69314718f, s, -0.36651292f);
}

// order-isomorphic u64 key: higher val wins; on equal val, LOWER idx wins
__device__ __forceinline__ unsigned long long pack_key(float val, int idx) {
  uint32_t fb = __float_as_uint(val);
  uint32_t key = (fb & 0x80000000u) ? ~fb : (fb | 0x80000000u);
  return ((unsigned long long)key << 32) |
         (unsigned long long)(0xFFFFFFFFu - (uint32_t)idx);
}

// ---------------- K1: LayerNorm + Q projection ----------------
__global__ __launch_bounds__(256, 4) void ln_qproj_kernel(
                                const float* __restrict__ queries,
                                const float* __restrict__ Wq,
                                const float* __restrict__ ln_g,
                                const float* __restrict__ ln_b,
                                float* __restrict__ q_ws) {
  __shared__ float xnT[QD][4];
  const int tid = threadIdx.x;
  const int wave = tid >> 6, lane = tid & 63;
  const int r0 = blockIdx.x * 4;
  const int r = r0 + wave;

  float vals[8];
  float s = 0.f;
#pragma unroll
  for (int j = 0; j < 8; ++j) { vals[j] = queries[r * QD + j * 64 + lane]; s += vals[j]; }
#pragma unroll
  for (int m = 32; m >= 1; m >>= 1) s += __shfl_xor(s, m, 64);
  const float mu = s * (1.f / 512.f);
  float ss = 0.f;
#pragma unroll
  for (int j = 0; j < 8; ++j) { float d = vals[j] - mu; ss += d * d; }
#pragma unroll
  for (int m = 32; m >= 1; m >>= 1) ss += __shfl_xor(ss, m, 64);
  const float rstd = 1.f / sqrtf(ss * (1.f / 512.f) + 1e-5f);
#pragma unroll
  for (int j = 0; j < 8; ++j) {
    int e = j * 64 + lane;
    xnT[e][wave] = (vals[j] - mu) * rstd * ln_g[e] + ln_b[e];
  }
  __syncthreads();

  const int e = blockIdx.y * 256 + tid;
  float a0 = 0.f, a1 = 0.f, a2 = 0.f, a3 = 0.f;
#pragma unroll 4
  for (int i = 0; i < QD; ++i) {
    f32x4 xv = *(const f32x4*)&xnT[i][0];
    float w = Wq[i * EMBD + e];
    a0 += xv.x * w; a1 += xv.y * w; a2 += xv.z * w; a3 += xv.w * w;
  }
  q_ws[(r0 + 0) * EMBD + e] = a0;
  q_ws[(r0 + 1) * EMBD + e] = a1;
  q_ws[(r0 + 2) * EMBD + e] = a2;
  q_ws[(r0 + 3) * EMBD + e] = a3;
}

// ---------------- K2: k = glove @ Wk, stored TRANSPOSED for score ----------------
// k_wsT float layout: ((h*16 + g)*VOCAB + v)*4 + dd  (g = 4-dim group, dd in [0,4))
#define BKk 60
__global__ __launch_bounds__(256, 4) void kproj_kernel(
                             const float* __restrict__ glove,
                             const float* __restrict__ Wk,
                             float* __restrict__ k_wsT) {
  __shared__ float AsT[BKk][68];
  __shared__ float Bs[BKk][64];
  const int tid = threadIdx.x;
  const int v0 = blockIdx.x * 64, n0 = blockIdx.y * 64;
  const int h = blockIdx.y;            // EMBD=512 -> each y-block is one head
  const int ty = tid >> 4, tx = tid & 15;
  f32x2 acc2[4][2] = {};
  for (int s = 0; s < 5; ++s) {
    const int w0 = s * BKk;
    __syncthreads();
    for (int f = tid; f < 64 * 15; f += 256) {
      int row = f / 15, c4 = f % 15;
      int v = v0 + row;
      float4 g4 = (v < VOCAB) ? *(const float4*)&glove[(size_t)v * WDn + w0 + c4 * 4]
                              : make_float4(0.f, 0.f, 0.f, 0.f);
      AsT[c4 * 4 + 0][row] = g4.x;
      AsT[c4 * 4 + 1][row] = g4.y;
      AsT[c4 * 4 + 2][row] = g4.z;
      AsT[c4 * 4 + 3][row] = g4.w;
    }
    for (int f = tid; f < BKk * 16; f += 256) {
      int row = f / 16, c4 = f % 16;
      *(float4*)&Bs[row][c4 * 4] = *(const float4*)&Wk[(size_t)(w0 + row) * EMBD + n0 + c4 * 4];
    }
    __syncthreads();
#pragma unroll 4
    for (int w = 0; w < BKk; ++w) {
      f32x4 aq = *(const f32x4*)&AsT[w][ty * 4];
      f32x4 bv = *(const f32x4*)&Bs[w][tx * 4];
      f32x2 bl = lo2(bv), bh = hi2(bv);
      f32x2 a01 = lo2(aq), a23 = hi2(aq);
      pk_fma_blo(acc2[0][0], a01, bl); pk_fma_blo(acc2[0][1], a01, bh);
      pk_fma_bhi(acc2[1][0], a01, bl); pk_fma_bhi(acc2[1][1], a01, bh);
      pk_fma_blo(acc2[2][0], a23, bl); pk_fma_blo(acc2[2][1], a23, bh);
      pk_fma_bhi(acc2[3][0], a23, bl); pk_fma_bhi(acc2[3][1], a23, bh);
    }
  }
#pragma unroll
  for (int i = 0; i < 4; ++i) {
    int v = v0 + ty * 4 + i;
    if (v < VOCAB) {
      float4 st = make_float4(acc2[i][0].x, acc2[i][0].y, acc2[i][1].x, acc2[i][1].y);
      // dims covered: h*64 + tx*4 .. +3  ->  g = tx
      *(float4*)&k_wsT[(size_t)((h * 16 + tx) * (size_t)VOCAB + v) * 4] = st;
    }
  }
}

// ---------------- K3: scores + gumbel + argmax; K direct-from-global ----------------
template<bool FULL>
__device__ __forceinline__ void score_epi(const f32x2 (&acc)[4][8],
                                          int v0, int tx, int ty, int rowtile, int h,
                                          unsigned long long* __restrict__ pk_buf) {
#pragma unroll
  for (int i = 0; i < 4; ++i) {
    const int r = rowtile * 64 + ty * 4 + i;
    const int b = r >> 7, q = r & 127;
    const int rowidx = (b * NH + h) * NQn + q;
    const uint32_t base = (uint32_t)rowidx * (uint32_t)VOCAB;

    uint32_t x0[8], x1[8];
#pragma unroll
    for (int j = 0; j < 8; ++j) {
      x0[j] = 0u;
      x1[j] = base + (uint32_t)(v0 + tx + 16 * j);
    }
    tf8(x0, x1);

    float best = -INFINITY; int bidx = 0x7fffffff;
#pragma unroll
    for (int j = 0; j < 8; ++j) {
      int v = v0 + tx + 16 * j;
      if (FULL || v < VOCAB) {
        float g = gumbel_from_bits(x0[j] ^ x1[j]);
        float val = (acc[i][j].x + acc[i][j].y) - g;  // q pre-scaled by 0.125
        if (val > best) { best = val; bidx = v; }     // v increasing -> lowest-idx ties
      }
    }
#pragma unroll
    for (int m = 8; m >= 1; m >>= 1) {
      float ov = __shfl_xor(best, m, 64);
      int   oi = __shfl_xor(bidx, m, 64);
      if (ov > best || (ov == best && oi < bidx)) { best = ov; bidx = oi; }
    }
    if (tx == 0) atomicMax(&pk_buf[rowidx], pack_key(best, bidx));
  }
}

// Only Q staged in LDS (17.4 KB). K read from global (transposed layout):
// per g-iter, lanes tx=0..15 read 16 consecutive v -> 256B contiguous, L1-friendly.
__global__ __launch_bounds__(256, 4) void score_kernel(
                  const float* __restrict__ q_ws,
                  const float* __restrict__ k_wsT,
                  unsigned long long* __restrict__ pk_buf) {
  __shared__ float Qs[64 * 68];
  const int tid = threadIdx.x;
  const int chunk = blockIdx.x, rowtile = blockIdx.y, h = blockIdx.z;
  const int v0 = chunk * VCHUNK;
  const int ty = tid >> 4, tx = tid & 15;

  for (int f = tid; f < 64 * 16; f += 256) {
    int row = f >> 4, c4 = f & 15;
    f32x4 qv = *(const f32x4*)&q_ws[(size_t)(rowtile * 64 + row) * EMBD + h * DHn + c4 * 4];
    qv *= 0.125f;                                    // fold scale (2^-3, exact)
    *(f32x4*)&Qs[row * 68 + c4 * 4] = qv;
  }
  __syncthreads();

  // per-column base pointers (clamped; clamped columns are discarded in epilogue)
  const float* kp[8];
#pragma unroll
  for (int j = 0; j < 8; ++j) {
    int v = v0 + tx + 16 * j;
    if (v > VOCAB - 1) v = VOCAB - 1;
    kp[j] = k_wsT + ((size_t)(h * 16) * (size_t)VOCAB + (size_t)v) * 4;
  }
  const size_t gstride = (size_t)VOCAB * 4;   // floats per g step

  f32x2 acc[4][8] = {};
#pragma unroll 1
  for (int g = 0; g < 16; ++g) {
    const size_t off = (size_t)g * gstride;
    f32x4 k0 = *(const f32x4*)(kp[0] + off);
    f32x4 k1 = *(const f32x4*)(kp[1] + off);
    f32x4 k2 = *(const f32x4*)(kp[2] + off);
    f32x4 k3 = *(const f32x4*)(kp[3] + off);
    f32x4 k4 = *(const f32x4*)(kp[4] + off);
    f32x4 k5 = *(const f32x4*)(kp[5] + off);
    f32x4 k6 = *(const f32x4*)(kp[6] + off);
    f32x4 k7 = *(const f32x4*)(kp[7] + off);
#pragma unroll
    for (int i = 0; i < 4; ++i) {
      f32x4 qv = *(const f32x4*)&Qs[(ty * 4 + i) * 68 + g * 4];
      f32x2 ql = lo2(qv), qh = hi2(qv);
      pk_fma(acc[i][0], ql, lo2(k0)); pk_fma(acc[i][0], qh, hi2(k0));
      pk_fma(acc[i][1], ql, lo2(k1)); pk_fma(acc[i][1], qh, hi2(k1));
      pk_fma(acc[i][2], ql, lo2(k2)); pk_fma(acc[i][2], qh, hi2(k2));
      pk_fma(acc[i][3], ql, lo2(k3)); pk_fma(acc[i][3], qh, hi2(k3));
      pk_fma(acc[i][4], ql, lo2(k4)); pk_fma(acc[i][4], qh, hi2(k4));
      pk_fma(acc[i][5], ql, lo2(k5)); pk_fma(acc[i][5], qh, hi2(k5));
      pk_fma(acc[i][6], ql, lo2(k6)); pk_fma(acc[i][6], qh, hi2(k6));
      pk_fma(acc[i][7], ql, lo2(k7)); pk_fma(acc[i][7], qh, hi2(k7));
    }
  }

  if (v0 + VCHUNK <= VOCAB)
    score_epi<true>(acc, v0, tx, ty, rowtile, h, pk_buf);
  else
    score_epi<false>(acc, v0, tx, ty, rowtile, h, pk_buf);
}

// ---------------- K5: gather + V projection + out proj + residual ----------------
__global__ __launch_bounds__(256, 4) void out_kernel(
                           const float* __restrict__ queries,
                           const float* __restrict__ glove,
                           const float* __restrict__ Wv,
                           const float* __restrict__ Wout,
                           const float* __restrict__ b_out,
                           const unsigned long long* __restrict__ pk_buf,
                           float* __restrict__ out) {
  __shared__ float gl[4][NH][WDn];
  __shared__ float vrow[4][EMBD];
  __shared__ int idxs[4][NH];
  const int tid = threadIdx.x;
  const int r0 = blockIdx.x * 4;
  if (tid < 32) {
    int rr = tid >> 3, hh = tid & 7;
    int r = r0 + rr, b = r >> 7, q = r & 127;
    unsigned long long p = pk_buf[(b * NH + hh) * NQn + q];
    idxs[rr][hh] = (int)(0xFFFFFFFFu - (uint32_t)(p & 0xFFFFFFFFull));
  }
  __syncthreads();
  for (int f = tid; f < 32 * 75; f += 256) {
    int rp = f / 75, c4 = f % 75;
    int rr = rp >> 3, hh = rp & 7;
    *(float4*)&gl[rr][hh][c4 * 4] = *(const float4*)&glove[(size_t)idxs[rr][hh] * WDn + c4 * 4];
  }
  __syncthreads();
  for (int e = tid; e < EMBD; e += 256) {
    float a0 = 0.f, a1 = 0.f, a2 = 0.f, a3 = 0.f;
    int hh = e >> 6;
    for (int w = 0; w < WDn; ++w) {
      float wv = Wv[(size_t)w * EMBD + e];
      a0 += gl[0][hh][w] * wv; a1 += gl[1][hh][w] * wv;
      a2 += gl[2][hh][w] * wv; a3 += gl[3][hh][w] * wv;
    }
    vrow[0][e] = a0; vrow[1][e] = a1; vrow[2][e] = a2; vrow[3][e] = a3;
  }
  __syncthreads();
  for (int j = tid; j < EMBD; j += 256) {
    float a0 = 0.f, a1 = 0.f, a2 = 0.f, a3 = 0.f;
    for (int e = 0; e < EMBD; ++e) {
      float wo = Wout[(size_t)e * QD + j];
      a0 += vrow[0][e] * wo; a1 += vrow[1][e] * wo;
      a2 += vrow[2][e] * wo; a3 += vrow[3][e] * wo;
    }
    float bb = b_out[j];
    out[(size_t)(r0 + 0) * QD + j] = queries[(size_t)(r0 + 0) * QD + j] + a0 + bb;
    out[(size_t)(r0 + 1) * QD + j] = queries[(size_t)(r0 + 1) * QD + j] + a1 + bb;
    out[(size_t)(r0 + 2) * QD + j] = queries[(size_t)(r0 + 2) * QD + j] + a2 + bb;
    out[(size_t)(r0 + 3) * QD + j] = queries[(size_t)(r0 + 3) * QD + j] + a3 + bb;
  }
}

extern "C" void kernel_launch(void* const* d_in, const int* in_sizes, int n_in,
                              void* d_out, int out_size, void* d_ws, size_t ws_size,
                              hipStream_t stream) {
  const float* queries = (const float*)d_in[0];
  const float* glove   = (const float*)d_in[1];
  const float* Wq      = (const float*)d_in[2];
  const float* Wk      = (const float*)d_in[3];
  const float* Wv      = (const float*)d_in[4];
  const float* Wout    = (const float*)d_in[5];
  const float* b_out   = (const float*)d_in[6];
  const float* ln_g    = (const float*)d_in[7];
  const float* ln_b    = (const float*)d_in[8];
  float* out = (float*)d_out;

  float* ws    = (float*)d_ws;
  float* q_ws  = ws;
  float* k_wsT = q_ws + (size_t)NB * NQn * EMBD;
  unsigned long long* pk_buf =
      (unsigned long long*)(k_wsT + (size_t)VOCAB * EMBD);

  hipMemsetAsync(pk_buf, 0, (size_t)NB * NH * NQn * sizeof(unsigned long long), stream);

  hipLaunchKernelGGL(ln_qproj_kernel, dim3(128, 2), dim3(256), 0, stream,
                     queries, Wq, ln_g, ln_b, q_ws);
  hipLaunchKernelGGL(kproj_kernel, dim3(313, 8), dim3(256), 0, stream,
                     glove, Wk, k_wsT);
  hipLaunchKernelGGL(score_kernel, dim3(NCHUNK, 8, NH), dim3(256), 0, stream,
                     q_ws, k_wsT, pk_buf);
  hipLaunchKernelGGL(out_kernel, dim3(128), dim3(256), 0, stream,
                     queries, glove, Wv, Wout, b_out, pk_buf, out);
}

// Round 12
// 497.824 us; speedup vs baseline: 1.2737x; 1.2737x over previous
//
#include <hip/hip_runtime.h>
#include <cstdint>
#include <cmath>

#define NB 4
#define NQn 128
#define QD 512
#define EMBD 512
#define NH 8
#define DHn 64
#define VOCAB 20000
#define WDn 300
#define VCHUNK 128
#define NCHUNK 157   // ceil(20000/128)

typedef float f32x4 __attribute__((ext_vector_type(4)));
typedef float f32x2 __attribute__((ext_vector_type(2)));
typedef short bf16x8 __attribute__((ext_vector_type(8)));

__device__ __forceinline__ f32x2 lo2(f32x4 v) { return __builtin_shufflevector(v, v, 0, 1); }
__device__ __forceinline__ f32x2 hi2(f32x4 v) { return __builtin_shufflevector(v, v, 2, 3); }

__device__ __forceinline__ void pk_fma_blo(f32x2 &d, f32x2 a, f32x2 b) {
  asm("v_pk_fma_f32 %0, %1, %2, %0 op_sel:[0,0,0] op_sel_hi:[0,1,1]"
      : "+v"(d) : "v"(a), "v"(b));
}
__device__ __forceinline__ void pk_fma_bhi(f32x2 &d, f32x2 a, f32x2 b) {
  asm("v_pk_fma_f32 %0, %1, %2, %0 op_sel:[1,0,0] op_sel_hi:[1,1,1]"
      : "+v"(d) : "v"(a), "v"(b));
}

__device__ __forceinline__ uint32_t rotl(uint32_t x, int r) {
  return __builtin_amdgcn_alignbit(x, x, 32 - r);
}

// pack two f32 -> two bf16 (lo = a, hi = b)
__device__ __forceinline__ uint32_t cvt_pk_bf16(float a, float b) {
  uint32_t r;
  asm("v_cvt_pk_bf16_f32 %0, %1, %2" : "=v"(r) : "v"(a), "v"(b));
  return r;
}

// 8 interleaved threefry2x32 chains (key=(0,42)); bits = out0 ^ out1 (verified R1)
#define TFK1 42u
#define TFK2 (0x1BD11BDAu ^ 42u)
__device__ __forceinline__ void tf8(uint32_t (&x0)[8], uint32_t (&x1)[8]) {
#define R8(r) \
  { _Pragma("unroll") for (int j = 0; j < 8; ++j) { x0[j] += x1[j]; x1[j] = rotl(x1[j], r); x1[j] ^= x0[j]; } }
#define K8(a, b) \
  { _Pragma("unroll") for (int j = 0; j < 8; ++j) { x0[j] += (a); x1[j] += (b); } }
  K8(0u, TFK1)
  R8(13) R8(15) R8(26) R8(6)  K8(TFK1, TFK2 + 1u)
  R8(17) R8(29) R8(16) R8(24) K8(TFK2, 0u + 2u)
  R8(13) R8(15) R8(26) R8(6)  K8(0u, TFK1 + 3u)
  R8(17) R8(29) R8(16) R8(24) K8(TFK1, TFK2 + 4u)
  R8(13) R8(15) R8(26) R8(6)  K8(TFK2, 0u + 5u)
#undef R8
#undef K8
}

__device__ __forceinline__ float gumbel_from_bits(uint32_t bits) {
  float f = __uint_as_float((bits >> 9) | 0x3f800000u) - 1.0f;
  float u = fmaxf(f, 1.17549435e-38f);
  float t = __log2f(u);
  float s = __log2f(-t);
  return fmaf(0.69314718f, s, -0.36651292f);
}

// order-isomorphic u64 key: higher val wins; on equal val, LOWER idx wins
__device__ __forceinline__ unsigned long long pack_key(float val, int idx) {
  uint32_t fb = __float_as_uint(val);
  uint32_t key = (fb & 0x80000000u) ? ~fb : (fb | 0x80000000u);
  return ((unsigned long long)key << 32) |
         (unsigned long long)(0xFFFFFFFFu - (uint32_t)idx);
}

// ---------------- K1: LayerNorm + Q projection ----------------
__global__ __launch_bounds__(256, 4) void ln_qproj_kernel(
                                const float* __restrict__ queries,
                                const float* __restrict__ Wq,
                                const float* __restrict__ ln_g,
                                const float* __restrict__ ln_b,
                                float* __restrict__ q_ws) {
  __shared__ float xnT[QD][4];
  const int tid = threadIdx.x;
  const int wave = tid >> 6, lane = tid & 63;
  const int r0 = blockIdx.x * 4;
  const int r = r0 + wave;

  float vals[8];
  float s = 0.f;
#pragma unroll
  for (int j = 0; j < 8; ++j) { vals[j] = queries[r * QD + j * 64 + lane]; s += vals[j]; }
#pragma unroll
  for (int m = 32; m >= 1; m >>= 1) s += __shfl_xor(s, m, 64);
  const float mu = s * (1.f / 512.f);
  float ss = 0.f;
#pragma unroll
  for (int j = 0; j < 8; ++j) { float d = vals[j] - mu; ss += d * d; }
#pragma unroll
  for (int m = 32; m >= 1; m >>= 1) ss += __shfl_xor(ss, m, 64);
  const float rstd = 1.f / sqrtf(ss * (1.f / 512.f) + 1e-5f);
#pragma unroll
  for (int j = 0; j < 8; ++j) {
    int e = j * 64 + lane;
    xnT[e][wave] = (vals[j] - mu) * rstd * ln_g[e] + ln_b[e];
  }
  __syncthreads();

  const int e = blockIdx.y * 256 + tid;
  float a0 = 0.f, a1 = 0.f, a2 = 0.f, a3 = 0.f;
#pragma unroll 4
  for (int i = 0; i < QD; ++i) {
    f32x4 xv = *(const f32x4*)&xnT[i][0];
    float w = Wq[i * EMBD + e];
    a0 += xv.x * w; a1 += xv.y * w; a2 += xv.z * w; a3 += xv.w * w;
  }
  q_ws[(r0 + 0) * EMBD + e] = a0;
  q_ws[(r0 + 1) * EMBD + e] = a1;
  q_ws[(r0 + 2) * EMBD + e] = a2;
  q_ws[(r0 + 3) * EMBD + e] = a3;
}

// ---------------- K2: k = glove @ Wk (bitwise-identical pk path) ----------------
#define BKk 60
__global__ __launch_bounds__(256, 4) void kproj_kernel(
                             const float* __restrict__ glove,
                             const float* __restrict__ Wk,
                             float* __restrict__ k_ws) {
  __shared__ float AsT[BKk][68];
  __shared__ float Bs[BKk][64];
  const int tid = threadIdx.x;
  const int v0 = blockIdx.x * 64, n0 = blockIdx.y * 64;
  const int ty = tid >> 4, tx = tid & 15;
  f32x2 acc2[4][2] = {};
  for (int s = 0; s < 5; ++s) {
    const int w0 = s * BKk;
    __syncthreads();
    for (int f = tid; f < 64 * 15; f += 256) {
      int row = f / 15, c4 = f % 15;
      int v = v0 + row;
      float4 g4 = (v < VOCAB) ? *(const float4*)&glove[(size_t)v * WDn + w0 + c4 * 4]
                              : make_float4(0.f, 0.f, 0.f, 0.f);
      AsT[c4 * 4 + 0][row] = g4.x;
      AsT[c4 * 4 + 1][row] = g4.y;
      AsT[c4 * 4 + 2][row] = g4.z;
      AsT[c4 * 4 + 3][row] = g4.w;
    }
    for (int f = tid; f < BKk * 16; f += 256) {
      int row = f / 16, c4 = f % 16;
      *(float4*)&Bs[row][c4 * 4] = *(const float4*)&Wk[(size_t)(w0 + row) * EMBD + n0 + c4 * 4];
    }
    __syncthreads();
#pragma unroll 4
    for (int w = 0; w < BKk; ++w) {
      f32x4 aq = *(const f32x4*)&AsT[w][ty * 4];
      f32x4 bv = *(const f32x4*)&Bs[w][tx * 4];
      f32x2 bl = lo2(bv), bh = hi2(bv);
      f32x2 a01 = lo2(aq), a23 = hi2(aq);
      pk_fma_blo(acc2[0][0], a01, bl); pk_fma_blo(acc2[0][1], a01, bh);
      pk_fma_bhi(acc2[1][0], a01, bl); pk_fma_bhi(acc2[1][1], a01, bh);
      pk_fma_blo(acc2[2][0], a23, bl); pk_fma_blo(acc2[2][1], a23, bh);
      pk_fma_bhi(acc2[3][0], a23, bl); pk_fma_bhi(acc2[3][1], a23, bh);
    }
  }
#pragma unroll
  for (int i = 0; i < 4; ++i) {
    int v = v0 + ty * 4 + i;
    if (v < VOCAB) {
      float4 st = make_float4(acc2[i][0].x, acc2[i][0].y, acc2[i][1].x, acc2[i][1].y);
      *(float4*)&k_ws[(size_t)v * EMBD + n0 + tx * 4] = st;
    }
  }
}

// ---------------- K3: MFMA split-bf16 scores + threefry gumbel + argmax ----------------
template<bool FULL>
__device__ __forceinline__ void score_epi(const f32x4 (&acc)[8],
                                          int v0, int tx, int ty, int rowtile, int h,
                                          unsigned long long* __restrict__ pk_buf) {
#pragma unroll
  for (int i = 0; i < 4; ++i) {
    const int r = rowtile * 64 + ty * 4 + i;     // row: MFMA C-layout == ty*4+i
    const int b = r >> 7, q = r & 127;
    const int rowidx = (b * NH + h) * NQn + q;
    const uint32_t base = (uint32_t)rowidx * (uint32_t)VOCAB;

    uint32_t x0[8], x1[8];
#pragma unroll
    for (int j = 0; j < 8; ++j) {
      x0[j] = 0u;
      x1[j] = base + (uint32_t)(v0 + tx + 16 * j);
    }
    tf8(x0, x1);

    float best = -INFINITY; int bidx = 0x7fffffff;
#pragma unroll
    for (int j = 0; j < 8; ++j) {
      int v = v0 + tx + 16 * j;
      if (FULL || v < VOCAB) {
        float g = gumbel_from_bits(x0[j] ^ x1[j]);
        float val = acc[j][i] - g;                // q pre-scaled by 0.125
        if (val > best) { best = val; bidx = v; } // v increasing -> lowest-idx ties
      }
    }
#pragma unroll
    for (int m = 8; m >= 1; m >>= 1) {
      float ov = __shfl_xor(best, m, 64);
      int   oi = __shfl_xor(bidx, m, 64);
      if (ov > best || (ov == best && oi < bidx)) { best = ov; bidx = oi; }
    }
    if (tx == 0) atomicMax(&pk_buf[rowidx], pack_key(best, bidx));
  }
}

// Block: 64 rows x 128 cols. Dot = split-bf16 4-term MFMA (matrix pipe),
// threefry/gumbel stays on VALU pipe -> pipes overlap (m114).
// LDS: Qh|Ql [64][64bf16] + Kh|Kl [128][64bf16] = 48KB, XOR-swizzled (row&7)<<4.
__global__ __launch_bounds__(256, 3) void score_kernel(
                  const float* __restrict__ q_ws,
                  const float* __restrict__ k_ws,
                  unsigned long long* __restrict__ pk_buf) {
  __shared__ uint4 lds4[3072];   // 48 KB
  char* const Qh = (char*)lds4;        // 8 KB  [64][128B]
  char* const Ql = Qh + 8192;          // 8 KB
  char* const Kh = Qh + 16384;         // 16 KB [128][128B]
  char* const Kl = Qh + 32768;         // 16 KB
  const int tid = threadIdx.x;
  const int chunk = blockIdx.x, rowtile = blockIdx.y, h = blockIdx.z;
  const int v0 = chunk * VCHUNK;
  const int tx = tid & 15, ty = tid >> 4;

  // stage Q (scaled by 0.125, exact), split to bf16 hi + bf16 residual
  for (int f = tid; f < 64 * 16; f += 256) {
    int row = f >> 4, c4 = f & 15;
    f32x4 qv = *(const f32x4*)&q_ws[(size_t)(rowtile * 64 + row) * EMBD + h * DHn + c4 * 4];
    qv *= 0.125f;
    uint32_t h01 = cvt_pk_bf16(qv.x, qv.y);
    uint32_t h23 = cvt_pk_bf16(qv.z, qv.w);
    float rx = qv.x - __uint_as_float(h01 << 16);
    float ry = qv.y - __uint_as_float(h01 & 0xFFFF0000u);
    float rz = qv.z - __uint_as_float(h23 << 16);
    float rw = qv.w - __uint_as_float(h23 & 0xFFFF0000u);
    uint32_t l01 = cvt_pk_bf16(rx, ry);
    uint32_t l23 = cvt_pk_bf16(rz, rw);
    int off = (row * 128 + c4 * 8) ^ ((row & 7) << 4);
    *(uint2*)(Qh + off) = make_uint2(h01, h23);
    *(uint2*)(Ql + off) = make_uint2(l01, l23);
  }
  // stage K split
  for (int f = tid; f < 128 * 16; f += 256) {
    int row = f >> 4, c4 = f & 15;
    int v = v0 + row;
    f32x4 kv = {0.f, 0.f, 0.f, 0.f};
    if (v < VOCAB) kv = *(const f32x4*)&k_ws[(size_t)v * EMBD + h * DHn + c4 * 4];
    uint32_t h01 = cvt_pk_bf16(kv.x, kv.y);
    uint32_t h23 = cvt_pk_bf16(kv.z, kv.w);
    float rx = kv.x - __uint_as_float(h01 << 16);
    float ry = kv.y - __uint_as_float(h01 & 0xFFFF0000u);
    float rz = kv.z - __uint_as_float(h23 << 16);
    float rw = kv.w - __uint_as_float(h23 & 0xFFFF0000u);
    uint32_t l01 = cvt_pk_bf16(rx, ry);
    uint32_t l23 = cvt_pk_bf16(rz, rw);
    int off = (row * 128 + c4 * 8) ^ ((row & 7) << 4);
    *(uint2*)(Kh + off) = make_uint2(h01, h23);
    *(uint2*)(Kl + off) = make_uint2(l01, l23);
  }
  __syncthreads();

  const int w = tid >> 6;          // wave id: rows w*16..w*16+15
  const int g4 = (tid >> 4) & 3;   // k-group within fragment
  const int swz = (tx & 7) << 4;   // row&7 == tx&7 for both A and B reads

  // A fragments: lane holds row=w*16+tx, k = g4*8 + [0..8) (+32 for kh=1)
  bf16x8 aH[2], aL[2];
  {
    const int abase = (w * 16 + tx) * 128 + g4 * 16;
#pragma unroll
    for (int kh = 0; kh < 2; ++kh) {
      int off = (abase + kh * 64) ^ swz;
      aH[kh] = *(const bf16x8*)(Qh + off);
      aL[kh] = *(const bf16x8*)(Ql + off);
    }
  }

  f32x4 acc[8] = {};
#pragma unroll
  for (int ct = 0; ct < 8; ++ct) {
    const int bbase = (ct * 16 + tx) * 128 + g4 * 16;
    bf16x8 bH[2], bL[2];
#pragma unroll
    for (int kh = 0; kh < 2; ++kh) {
      int off = (bbase + kh * 64) ^ swz;
      bH[kh] = *(const bf16x8*)(Kh + off);
      bL[kh] = *(const bf16x8*)(Kl + off);
    }
    acc[ct] = __builtin_amdgcn_mfma_f32_16x16x32_bf16(aH[0], bH[0], acc[ct], 0, 0, 0);
    acc[ct] = __builtin_amdgcn_mfma_f32_16x16x32_bf16(aH[1], bH[1], acc[ct], 0, 0, 0);
    acc[ct] = __builtin_amdgcn_mfma_f32_16x16x32_bf16(aH[0], bL[0], acc[ct], 0, 0, 0);
    acc[ct] = __builtin_amdgcn_mfma_f32_16x16x32_bf16(aH[1], bL[1], acc[ct], 0, 0, 0);
    acc[ct] = __builtin_amdgcn_mfma_f32_16x16x32_bf16(aL[0], bH[0], acc[ct], 0, 0, 0);
    acc[ct] = __builtin_amdgcn_mfma_f32_16x16x32_bf16(aL[1], bH[1], acc[ct], 0, 0, 0);
    acc[ct] = __builtin_amdgcn_mfma_f32_16x16x32_bf16(aL[0], bL[0], acc[ct], 0, 0, 0);
    acc[ct] = __builtin_amdgcn_mfma_f32_16x16x32_bf16(aL[1], bL[1], acc[ct], 0, 0, 0);
  }

  if (v0 + VCHUNK <= VOCAB)
    score_epi<true>(acc, v0, tx, ty, rowtile, h, pk_buf);
  else
    score_epi<false>(acc, v0, tx, ty, rowtile, h, pk_buf);
}

// ---------------- K5: gather + V projection + out proj + residual ----------------
__global__ __launch_bounds__(256, 4) void out_kernel(
                           const float* __restrict__ queries,
                           const float* __restrict__ glove,
                           const float* __restrict__ Wv,
                           const float* __restrict__ Wout,
                           const float* __restrict__ b_out,
                           const unsigned long long* __restrict__ pk_buf,
                           float* __restrict__ out) {
  __shared__ float gl[4][NH][WDn];
  __shared__ float vrow[4][EMBD];
  __shared__ int idxs[4][NH];
  const int tid = threadIdx.x;
  const int r0 = blockIdx.x * 4;
  if (tid < 32) {
    int rr = tid >> 3, hh = tid & 7;
    int r = r0 + rr, b = r >> 7, q = r & 127;
    unsigned long long p = pk_buf[(b * NH + hh) * NQn + q];
    idxs[rr][hh] = (int)(0xFFFFFFFFu - (uint32_t)(p & 0xFFFFFFFFull));
  }
  __syncthreads();
  for (int f = tid; f < 32 * 75; f += 256) {
    int rp = f / 75, c4 = f % 75;
    int rr = rp >> 3, hh = rp & 7;
    *(float4*)&gl[rr][hh][c4 * 4] = *(const float4*)&glove[(size_t)idxs[rr][hh] * WDn + c4 * 4];
  }
  __syncthreads();
  for (int e = tid; e < EMBD; e += 256) {
    float a0 = 0.f, a1 = 0.f, a2 = 0.f, a3 = 0.f;
    int hh = e >> 6;
    for (int w = 0; w < WDn; ++w) {
      float wv = Wv[(size_t)w * EMBD + e];
      a0 += gl[0][hh][w] * wv; a1 += gl[1][hh][w] * wv;
      a2 += gl[2][hh][w] * wv; a3 += gl[3][hh][w] * wv;
    }
    vrow[0][e] = a0; vrow[1][e] = a1; vrow[2][e] = a2; vrow[3][e] = a3;
  }
  __syncthreads();
  for (int j = tid; j < EMBD; j += 256) {
    float a0 = 0.f, a1 = 0.f, a2 = 0.f, a3 = 0.f;
    for (int e = 0; e < EMBD; ++e) {
      float wo = Wout[(size_t)e * QD + j];
      a0 += vrow[0][e] * wo; a1 += vrow[1][e] * wo;
      a2 += vrow[2][e] * wo; a3 += vrow[3][e] * wo;
    }
    float bb = b_out[j];
    out[(size_t)(r0 + 0) * QD + j] = queries[(size_t)(r0 + 0) * QD + j] + a0 + bb;
    out[(size_t)(r0 + 1) * QD + j] = queries[(size_t)(r0 + 1) * QD + j] + a1 + bb;
    out[(size_t)(r0 + 2) * QD + j] = queries[(size_t)(r0 + 2) * QD + j] + a2 + bb;
    out[(size_t)(r0 + 3) * QD + j] = queries[(size_t)(r0 + 3) * QD + j] + a3 + bb;
  }
}

extern "C" void kernel_launch(void* const* d_in, const int* in_sizes, int n_in,
                              void* d_out, int out_size, void* d_ws, size_t ws_size,
                              hipStream_t stream) {
  const float* queries = (const float*)d_in[0];
  const float* glove   = (const float*)d_in[1];
  const float* Wq      = (const float*)d_in[2];
  const float* Wk      = (const float*)d_in[3];
  const float* Wv      = (const float*)d_in[4];
  const float* Wout    = (const float*)d_in[5];
  const float* b_out   = (const float*)d_in[6];
  const float* ln_g    = (const float*)d_in[7];
  const float* ln_b    = (const float*)d_in[8];
  float* out = (float*)d_out;

  float* ws   = (float*)d_ws;
  float* q_ws = ws;
  float* k_ws = q_ws + (size_t)NB * NQn * EMBD;
  unsigned long long* pk_buf =
      (unsigned long long*)(k_ws + (size_t)VOCAB * EMBD);

  hipMemsetAsync(pk_buf, 0, (size_t)NB * NH * NQn * sizeof(unsigned long long), stream);

  hipLaunchKernelGGL(ln_qproj_kernel, dim3(128, 2), dim3(256), 0, stream,
                     queries, Wq, ln_g, ln_b, q_ws);
  hipLaunchKernelGGL(kproj_kernel, dim3(313, 8), dim3(256), 0, stream,
                     glove, Wk, k_ws);
  hipLaunchKernelGGL(score_kernel, dim3(NCHUNK, 8, NH), dim3(256), 0, stream,
                     q_ws, k_ws, pk_buf);
  hipLaunchKernelGGL(out_kernel, dim3(128), dim3(256), 0, stream,
                     queries, glove, Wv, Wout, b_out, pk_buf, out);
}

// Round 13
// 430.478 us; speedup vs baseline: 1.4730x; 1.1564x over previous
//
#include <hip/hip_runtime.h>
#include <cstdint>
#include <cmath>

#define NB 4
#define NQn 128
#define QD 512
#define EMBD 512
#define NH 8
#define DHn 64
#define VOCAB 20000
#define WDn 300
#define VCHUNK 128
#define NCHUNK 157   // ceil(20000/128)

typedef float f32x4 __attribute__((ext_vector_type(4)));
typedef float f32x2 __attribute__((ext_vector_type(2)));
typedef short bf16x8 __attribute__((ext_vector_type(8)));

__device__ __forceinline__ f32x2 lo2(f32x4 v) { return __builtin_shufflevector(v, v, 0, 1); }
__device__ __forceinline__ f32x2 hi2(f32x4 v) { return __builtin_shufflevector(v, v, 2, 3); }

__device__ __forceinline__ void pk_fma_blo(f32x2 &d, f32x2 a, f32x2 b) {
  asm("v_pk_fma_f32 %0, %1, %2, %0 op_sel:[0,0,0] op_sel_hi:[0,1,1]"
      : "+v"(d) : "v"(a), "v"(b));
}
__device__ __forceinline__ void pk_fma_bhi(f32x2 &d, f32x2 a, f32x2 b) {
  asm("v_pk_fma_f32 %0, %1, %2, %0 op_sel:[1,0,0] op_sel_hi:[1,1,1]"
      : "+v"(d) : "v"(a), "v"(b));
}

__device__ __forceinline__ uint32_t rotl(uint32_t x, int r) {
  return __builtin_amdgcn_alignbit(x, x, 32 - r);
}

// pack two f32 -> two bf16 (lo = a, hi = b), RNE
__device__ __forceinline__ uint32_t cvt_pk_bf16(float a, float b) {
  uint32_t r;
  asm("v_cvt_pk_bf16_f32 %0, %1, %2" : "=v"(r) : "v"(a), "v"(b));
  return r;
}

// split f32x4 -> bf16 hi (RNE) + bf16 residual; identical math to R12 (verified)
__device__ __forceinline__ void split4(f32x4 v, uint2 &hi, uint2 &lo) {
  uint32_t h01 = cvt_pk_bf16(v.x, v.y);
  uint32_t h23 = cvt_pk_bf16(v.z, v.w);
  float rx = v.x - __uint_as_float(h01 << 16);
  float ry = v.y - __uint_as_float(h01 & 0xFFFF0000u);
  float rz = v.z - __uint_as_float(h23 << 16);
  float rw = v.w - __uint_as_float(h23 & 0xFFFF0000u);
  hi = make_uint2(h01, h23);
  lo = make_uint2(cvt_pk_bf16(rx, ry), cvt_pk_bf16(rz, rw));
}

// 8 interleaved threefry2x32 chains (key=(0,42)); bits = out0 ^ out1 (verified R1)
#define TFK1 42u
#define TFK2 (0x1BD11BDAu ^ 42u)
__device__ __forceinline__ void tf8(uint32_t (&x0)[8], uint32_t (&x1)[8]) {
#define R8(r) \
  { _Pragma("unroll") for (int j = 0; j < 8; ++j) { x0[j] += x1[j]; x1[j] = rotl(x1[j], r); x1[j] ^= x0[j]; } }
#define K8(a, b) \
  { _Pragma("unroll") for (int j = 0; j < 8; ++j) { x0[j] += (a); x1[j] += (b); } }
  K8(0u, TFK1)
  R8(13) R8(15) R8(26) R8(6)  K8(TFK1, TFK2 + 1u)
  R8(17) R8(29) R8(16) R8(24) K8(TFK2, 0u + 2u)
  R8(13) R8(15) R8(26) R8(6)  K8(0u, TFK1 + 3u)
  R8(17) R8(29) R8(16) R8(24) K8(TFK1, TFK2 + 4u)
  R8(13) R8(15) R8(26) R8(6)  K8(TFK2, 0u + 5u)
#undef R8
#undef K8
}

__device__ __forceinline__ float gumbel_from_bits(uint32_t bits) {
  float f = __uint_as_float((bits >> 9) | 0x3f800000u) - 1.0f;
  float u = fmaxf(f, 1.17549435e-38f);
  float t = __log2f(u);
  float s = __log2f(-t);
  return fmaf(0.69314718f, s, -0.36651292f);
}

// order-isomorphic u64 key: higher val wins; on equal val, LOWER idx wins
__device__ __forceinline__ unsigned long long pack_key(float val, int idx) {
  uint32_t fb = __float_as_uint(val);
  uint32_t key = (fb & 0x80000000u) ? ~fb : (fb | 0x80000000u);
  return ((unsigned long long)key << 32) |
         (unsigned long long)(0xFFFFFFFFu - (uint32_t)idx);
}

// ---------------- K1: LayerNorm + Q projection -> split bf16 (q*0.125) ----------------
__global__ __launch_bounds__(256, 4) void ln_qproj_kernel(
                                const float* __restrict__ queries,
                                const float* __restrict__ Wq,
                                const float* __restrict__ ln_g,
                                const float* __restrict__ ln_b,
                                ushort* __restrict__ qh_ws,
                                ushort* __restrict__ ql_ws) {
  __shared__ float xnT[QD][4];
  const int tid = threadIdx.x;
  const int wave = tid >> 6, lane = tid & 63;
  const int r0 = blockIdx.x * 4;
  const int r = r0 + wave;

  float vals[8];
  float s = 0.f;
#pragma unroll
  for (int j = 0; j < 8; ++j) { vals[j] = queries[r * QD + j * 64 + lane]; s += vals[j]; }
#pragma unroll
  for (int m = 32; m >= 1; m >>= 1) s += __shfl_xor(s, m, 64);
  const float mu = s * (1.f / 512.f);
  float ss = 0.f;
#pragma unroll
  for (int j = 0; j < 8; ++j) { float d = vals[j] - mu; ss += d * d; }
#pragma unroll
  for (int m = 32; m >= 1; m >>= 1) ss += __shfl_xor(ss, m, 64);
  const float rstd = 1.f / sqrtf(ss * (1.f / 512.f) + 1e-5f);
#pragma unroll
  for (int j = 0; j < 8; ++j) {
    int e = j * 64 + lane;
    xnT[e][wave] = (vals[j] - mu) * rstd * ln_g[e] + ln_b[e];
  }
  __syncthreads();

  const int e = blockIdx.y * 256 + tid;   // global output column
  float a0 = 0.f, a1 = 0.f, a2 = 0.f, a3 = 0.f;
#pragma unroll 4
  for (int i = 0; i < QD; ++i) {
    f32x4 xv = *(const f32x4*)&xnT[i][0];
    float w = Wq[i * EMBD + e];
    a0 += xv.x * w; a1 += xv.y * w; a2 += xv.z * w; a3 += xv.w * w;
  }
  // write split bf16 of q*0.125 (exact scale; same values R12 split in-score)
  const int h = e >> 6, d = e & 63;
  float aa[4] = {a0, a1, a2, a3};
#pragma unroll
  for (int i = 0; i < 4; ++i) {
    float q = aa[i] * 0.125f;
    uint32_t hp = cvt_pk_bf16(q, q);        // lo half = bf16(q)
    float resid = q - __uint_as_float(hp << 16);
    uint32_t lp = cvt_pk_bf16(resid, resid);
    size_t off = ((size_t)h * 512 + (r0 + i)) * 64 + d;
    qh_ws[off] = (ushort)(hp & 0xFFFFu);
    ql_ws[off] = (ushort)(lp & 0xFFFFu);
  }
}

// ---------------- K2: k = glove @ Wk -> split bf16 hi/lo ----------------
#define BKk 60
__global__ __launch_bounds__(256, 4) void kproj_kernel(
                             const float* __restrict__ glove,
                             const float* __restrict__ Wk,
                             ushort* __restrict__ kh_ws,
                             ushort* __restrict__ kl_ws) {
  __shared__ float AsT[BKk][68];
  __shared__ float Bs[BKk][64];
  const int tid = threadIdx.x;
  const int v0 = blockIdx.x * 64;
  const int h = blockIdx.y;            // EMBD=512 -> y-block = head, dims h*64..
  const int n0 = h * 64;
  const int ty = tid >> 4, tx = tid & 15;
  f32x2 acc2[4][2] = {};
  for (int s = 0; s < 5; ++s) {
    const int w0 = s * BKk;
    __syncthreads();
    for (int f = tid; f < 64 * 15; f += 256) {
      int row = f / 15, c4 = f % 15;
      int v = v0 + row;
      float4 g4 = (v < VOCAB) ? *(const float4*)&glove[(size_t)v * WDn + w0 + c4 * 4]
                              : make_float4(0.f, 0.f, 0.f, 0.f);
      AsT[c4 * 4 + 0][row] = g4.x;
      AsT[c4 * 4 + 1][row] = g4.y;
      AsT[c4 * 4 + 2][row] = g4.z;
      AsT[c4 * 4 + 3][row] = g4.w;
    }
    for (int f = tid; f < BKk * 16; f += 256) {
      int row = f / 16, c4 = f % 16;
      *(float4*)&Bs[row][c4 * 4] = *(const float4*)&Wk[(size_t)(w0 + row) * EMBD + n0 + c4 * 4];
    }
    __syncthreads();
#pragma unroll 4
    for (int w = 0; w < BKk; ++w) {
      f32x4 aq = *(const f32x4*)&AsT[w][ty * 4];
      f32x4 bv = *(const f32x4*)&Bs[w][tx * 4];
      f32x2 bl = lo2(bv), bh = hi2(bv);
      f32x2 a01 = lo2(aq), a23 = hi2(aq);
      pk_fma_blo(acc2[0][0], a01, bl); pk_fma_blo(acc2[0][1], a01, bh);
      pk_fma_bhi(acc2[1][0], a01, bl); pk_fma_bhi(acc2[1][1], a01, bh);
      pk_fma_blo(acc2[2][0], a23, bl); pk_fma_blo(acc2[2][1], a23, bh);
      pk_fma_bhi(acc2[3][0], a23, bl); pk_fma_bhi(acc2[3][1], a23, bh);
    }
  }
#pragma unroll
  for (int i = 0; i < 4; ++i) {
    int v = v0 + ty * 4 + i;
    if (v < VOCAB) {
      f32x4 kv = {acc2[i][0].x, acc2[i][0].y, acc2[i][1].x, acc2[i][1].y};
      uint2 hi, lo;
      split4(kv, hi, lo);    // identical conversion R12 performed in-score
      size_t off = ((size_t)h * VOCAB + v) * 64 + tx * 4;
      *(uint2*)&kh_ws[off] = hi;
      *(uint2*)&kl_ws[off] = lo;
    }
  }
}

// ---------------- K3: MFMA split-bf16 scores + threefry gumbel + argmax ----------------
template<bool FULL>
__device__ __forceinline__ void score_epi(const f32x4 (&acc)[8],
                                          int v0, int tx, int ty, int rowtile, int h,
                                          unsigned long long* __restrict__ pk_buf) {
#pragma unroll
  for (int i = 0; i < 4; ++i) {
    const int r = rowtile * 64 + ty * 4 + i;     // verified C-layout row mapping
    const int b = r >> 7, q = r & 127;
    const int rowidx = (b * NH + h) * NQn + q;
    const uint32_t base = (uint32_t)rowidx * (uint32_t)VOCAB;

    uint32_t x0[8], x1[8];
#pragma unroll
    for (int j = 0; j < 8; ++j) {
      x0[j] = 0u;
      x1[j] = base + (uint32_t)(v0 + tx + 16 * j);
    }
    tf8(x0, x1);

    float best = -INFINITY; int bidx = 0x7fffffff;
#pragma unroll
    for (int j = 0; j < 8; ++j) {
      int v = v0 + tx + 16 * j;
      if (FULL || v < VOCAB) {
        float g = gumbel_from_bits(x0[j] ^ x1[j]);
        float val = acc[j][i] - g;                // q pre-scaled by 0.125
        if (val > best) { best = val; bidx = v; } // v increasing -> lowest-idx ties
      }
    }
#pragma unroll
    for (int m = 8; m >= 1; m >>= 1) {
      float ov = __shfl_xor(best, m, 64);
      int   oi = __shfl_xor(bidx, m, 64);
      if (ov > best || (ov == best && oi < bidx)) { best = ov; bidx = oi; }
    }
    if (tx == 0) atomicMax(&pk_buf[rowidx], pack_key(best, bidx));
  }
}

// 64 rows x 128 cols per block. LDS = swizzled Kh|Kl only (32 KB -> 5 blocks/CU).
// Q fragments loaded per-lane from precomputed global split arrays.
__global__ __launch_bounds__(256, 5) void score_kernel(
                  const ushort* __restrict__ qh_ws,
                  const ushort* __restrict__ ql_ws,
                  const ushort* __restrict__ kh_ws,
                  const ushort* __restrict__ kl_ws,
                  unsigned long long* __restrict__ pk_buf) {
  __shared__ uint4 lds4[2048];         // 32 KB
  char* const Kh = (char*)lds4;        // 16 KB [128][128B] swizzled
  char* const Kl = Kh + 16384;         // 16 KB
  const int tid = threadIdx.x;
  const int chunk = blockIdx.x, rowtile = blockIdx.y, h = blockIdx.z;
  const int v0 = chunk * VCHUNK;
  const int tx = tid & 15, ty = tid >> 4;
  const int w = tid >> 6;              // wave id: rows w*16..+15
  const int g4 = (tid >> 4) & 3;       // k-group
  const int swz = (tx & 7) << 4;

  // A fragments from global (private per lane; no LDS round-trip)
  bf16x8 aH[2], aL[2];
  {
    const size_t qbase = ((size_t)h * 512 + rowtile * 64 + w * 16 + tx) * 64 + g4 * 8;
#pragma unroll
    for (int kh = 0; kh < 2; ++kh) {
      aH[kh] = *(const bf16x8*)(qh_ws + qbase + kh * 32);
      aL[kh] = *(const bf16x8*)(ql_ws + qbase + kh * 32);
    }
  }

  // stage K tile (pure copy, swizzled ds_write)
  for (int f = tid; f < 128 * 8; f += 256) {
    int row = f >> 3, c8 = f & 7;
    int v = v0 + row;
    uint4 vh = {0u, 0u, 0u, 0u}, vl = {0u, 0u, 0u, 0u};
    if (v < VOCAB) {
      size_t off = ((size_t)h * VOCAB + v) * 64 + c8 * 8;
      vh = *(const uint4*)(kh_ws + off);
      vl = *(const uint4*)(kl_ws + off);
    }
    int loff = (row * 128 + c8 * 16) ^ ((row & 7) << 4);
    *(uint4*)(Kh + loff) = vh;
    *(uint4*)(Kl + loff) = vl;
  }
  __syncthreads();

  f32x4 acc[8] = {};
#pragma unroll
  for (int ct = 0; ct < 8; ++ct) {
    const int bbase = (ct * 16 + tx) * 128 + g4 * 16;
    bf16x8 bH[2], bL[2];
#pragma unroll
    for (int kh = 0; kh < 2; ++kh) {
      int off = (bbase + kh * 64) ^ swz;
      bH[kh] = *(const bf16x8*)(Kh + off);
      bL[kh] = *(const bf16x8*)(Kl + off);
    }
    acc[ct] = __builtin_amdgcn_mfma_f32_16x16x32_bf16(aH[0], bH[0], acc[ct], 0, 0, 0);
    acc[ct] = __builtin_amdgcn_mfma_f32_16x16x32_bf16(aH[1], bH[1], acc[ct], 0, 0, 0);
    acc[ct] = __builtin_amdgcn_mfma_f32_16x16x32_bf16(aH[0], bL[0], acc[ct], 0, 0, 0);
    acc[ct] = __builtin_amdgcn_mfma_f32_16x16x32_bf16(aH[1], bL[1], acc[ct], 0, 0, 0);
    acc[ct] = __builtin_amdgcn_mfma_f32_16x16x32_bf16(aL[0], bH[0], acc[ct], 0, 0, 0);
    acc[ct] = __builtin_amdgcn_mfma_f32_16x16x32_bf16(aL[1], bH[1], acc[ct], 0, 0, 0);
    acc[ct] = __builtin_amdgcn_mfma_f32_16x16x32_bf16(aL[0], bL[0], acc[ct], 0, 0, 0);
    acc[ct] = __builtin_amdgcn_mfma_f32_16x16x32_bf16(aL[1], bL[1], acc[ct], 0, 0, 0);
  }

  if (v0 + VCHUNK <= VOCAB)
    score_epi<true>(acc, v0, tx, ty, rowtile, h, pk_buf);
  else
    score_epi<false>(acc, v0, tx, ty, rowtile, h, pk_buf);
}

// ---------------- K5: gather + V projection + out proj + residual ----------------
__global__ __launch_bounds__(256, 4) void out_kernel(
                           const float* __restrict__ queries,
                           const float* __restrict__ glove,
                           const float* __restrict__ Wv,
                           const float* __restrict__ Wout,
                           const float* __restrict__ b_out,
                           const unsigned long long* __restrict__ pk_buf,
                           float* __restrict__ out) {
  __shared__ float gl[4][NH][WDn];
  __shared__ float vrow[4][EMBD];
  __shared__ int idxs[4][NH];
  const int tid = threadIdx.x;
  const int r0 = blockIdx.x * 4;
  if (tid < 32) {
    int rr = tid >> 3, hh = tid & 7;
    int r = r0 + rr, b = r >> 7, q = r & 127;
    unsigned long long p = pk_buf[(b * NH + hh) * NQn + q];
    idxs[rr][hh] = (int)(0xFFFFFFFFu - (uint32_t)(p & 0xFFFFFFFFull));
  }
  __syncthreads();
  for (int f = tid; f < 32 * 75; f += 256) {
    int rp = f / 75, c4 = f % 75;
    int rr = rp >> 3, hh = rp & 7;
    *(float4*)&gl[rr][hh][c4 * 4] = *(const float4*)&glove[(size_t)idxs[rr][hh] * WDn + c4 * 4];
  }
  __syncthreads();
  for (int e = tid; e < EMBD; e += 256) {
    float a0 = 0.f, a1 = 0.f, a2 = 0.f, a3 = 0.f;
    int hh = e >> 6;
    for (int w = 0; w < WDn; ++w) {
      float wv = Wv[(size_t)w * EMBD + e];
      a0 += gl[0][hh][w] * wv; a1 += gl[1][hh][w] * wv;
      a2 += gl[2][hh][w] * wv; a3 += gl[3][hh][w] * wv;
    }
    vrow[0][e] = a0; vrow[1][e] = a1; vrow[2][e] = a2; vrow[3][e] = a3;
  }
  __syncthreads();
  for (int j = tid; j < EMBD; j += 256) {
    float a0 = 0.f, a1 = 0.f, a2 = 0.f, a3 = 0.f;
    for (int e = 0; e < EMBD; ++e) {
      float wo = Wout[(size_t)e * QD + j];
      a0 += vrow[0][e] * wo; a1 += vrow[1][e] * wo;
      a2 += vrow[2][e] * wo; a3 += vrow[3][e] * wo;
    }
    float bb = b_out[j];
    out[(size_t)(r0 + 0) * QD + j] = queries[(size_t)(r0 + 0) * QD + j] + a0 + bb;
    out[(size_t)(r0 + 1) * QD + j] = queries[(size_t)(r0 + 1) * QD + j] + a1 + bb;
    out[(size_t)(r0 + 2) * QD + j] = queries[(size_t)(r0 + 2) * QD + j] + a2 + bb;
    out[(size_t)(r0 + 3) * QD + j] = queries[(size_t)(r0 + 3) * QD + j] + a3 + bb;
  }
}

extern "C" void kernel_launch(void* const* d_in, const int* in_sizes, int n_in,
                              void* d_out, int out_size, void* d_ws, size_t ws_size,
                              hipStream_t stream) {
  const float* queries = (const float*)d_in[0];
  const float* glove   = (const float*)d_in[1];
  const float* Wq      = (const float*)d_in[2];
  const float* Wk      = (const float*)d_in[3];
  const float* Wv      = (const float*)d_in[4];
  const float* Wout    = (const float*)d_in[5];
  const float* b_out   = (const float*)d_in[6];
  const float* ln_g    = (const float*)d_in[7];
  const float* ln_b    = (const float*)d_in[8];
  float* out = (float*)d_out;

  // ws layout: qh[256K us] | ql[256K us] | kh[10.24M us] | kl[10.24M us] | pk_buf
  char* ws = (char*)d_ws;
  ushort* qh_ws = (ushort*)ws;
  ushort* ql_ws = qh_ws + (size_t)NH * 512 * 64;
  ushort* kh_ws = ql_ws + (size_t)NH * 512 * 64;
  ushort* kl_ws = kh_ws + (size_t)NH * VOCAB * 64;
  unsigned long long* pk_buf = (unsigned long long*)(kl_ws + (size_t)NH * VOCAB * 64);

  hipMemsetAsync(pk_buf, 0, (size_t)NB * NH * NQn * sizeof(unsigned long long), stream);

  hipLaunchKernelGGL(ln_qproj_kernel, dim3(128, 2), dim3(256), 0, stream,
                     queries, Wq, ln_g, ln_b, qh_ws, ql_ws);
  hipLaunchKernelGGL(kproj_kernel, dim3(313, 8), dim3(256), 0, stream,
                     glove, Wk, kh_ws, kl_ws);
  hipLaunchKernelGGL(score_kernel, dim3(NCHUNK, 8, NH), dim3(256), 0, stream,
                     qh_ws, ql_ws, kh_ws, kl_ws, pk_buf);
  hipLaunchKernelGGL(out_kernel, dim3(128), dim3(256), 0, stream,
                     queries, glove, Wv, Wout, b_out, pk_buf, out);
}

// Round 14
// 346.736 us; speedup vs baseline: 1.8288x; 1.2415x over previous
//
#include <hip/hip_runtime.h>
#include <cstdint>
#include <cmath>

#define NB 4
#define NQn 128
#define QD 512
#define EMBD 512
#define NH 8
#define DHn 64
#define VOCAB 20000
#define WDn 300
#define VCHUNK 128
#define NCHUNK 157   // ceil(20000/128)

typedef float f32x4 __attribute__((ext_vector_type(4)));
typedef float f32x2 __attribute__((ext_vector_type(2)));
typedef short bf16x8 __attribute__((ext_vector_type(8)));

__device__ __forceinline__ f32x2 lo2(f32x4 v) { return __builtin_shufflevector(v, v, 0, 1); }
__device__ __forceinline__ f32x2 hi2(f32x4 v) { return __builtin_shufflevector(v, v, 2, 3); }

__device__ __forceinline__ void pk_fma_blo(f32x2 &d, f32x2 a, f32x2 b) {
  asm("v_pk_fma_f32 %0, %1, %2, %0 op_sel:[0,0,0] op_sel_hi:[0,1,1]"
      : "+v"(d) : "v"(a), "v"(b));
}
__device__ __forceinline__ void pk_fma_bhi(f32x2 &d, f32x2 a, f32x2 b) {
  asm("v_pk_fma_f32 %0, %1, %2, %0 op_sel:[1,0,0] op_sel_hi:[1,1,1]"
      : "+v"(d) : "v"(a), "v"(b));
}

__device__ __forceinline__ uint32_t rotl(uint32_t x, int r) {
  return __builtin_amdgcn_alignbit(x, x, 32 - r);
}

__device__ __forceinline__ uint32_t cvt_pk_bf16(float a, float b) {
  uint32_t r;
  asm("v_cvt_pk_bf16_f32 %0, %1, %2" : "=v"(r) : "v"(a), "v"(b));
  return r;
}

// split f32x4 -> bf16 hi (RNE) + bf16 residual (verified R12/R13)
__device__ __forceinline__ void split4(f32x4 v, uint2 &hi, uint2 &lo) {
  uint32_t h01 = cvt_pk_bf16(v.x, v.y);
  uint32_t h23 = cvt_pk_bf16(v.z, v.w);
  float rx = v.x - __uint_as_float(h01 << 16);
  float ry = v.y - __uint_as_float(h01 & 0xFFFF0000u);
  float rz = v.z - __uint_as_float(h23 << 16);
  float rw = v.w - __uint_as_float(h23 & 0xFFFF0000u);
  hi = make_uint2(h01, h23);
  lo = make_uint2(cvt_pk_bf16(rx, ry), cvt_pk_bf16(rz, rw));
}

// 8 interleaved threefry2x32 chains (key=(0,42)); bits = out0 ^ out1 (verified R1)
#define TFK1 42u
#define TFK2 (0x1BD11BDAu ^ 42u)
__device__ __forceinline__ void tf8(uint32_t (&x0)[8], uint32_t (&x1)[8]) {
#define R8(r) \
  { _Pragma("unroll") for (int j = 0; j < 8; ++j) { x0[j] += x1[j]; x1[j] = rotl(x1[j], r); x1[j] ^= x0[j]; } }
#define K8(a, b) \
  { _Pragma("unroll") for (int j = 0; j < 8; ++j) { x0[j] += (a); x1[j] += (b); } }
  K8(0u, TFK1)
  R8(13) R8(15) R8(26) R8(6)  K8(TFK1, TFK2 + 1u)
  R8(17) R8(29) R8(16) R8(24) K8(TFK2, 0u + 2u)
  R8(13) R8(15) R8(26) R8(6)  K8(0u, TFK1 + 3u)
  R8(17) R8(29) R8(16) R8(24) K8(TFK1, TFK2 + 4u)
  R8(13) R8(15) R8(26) R8(6)  K8(TFK2, 0u + 5u)
#undef R8
#undef K8
}

__device__ __forceinline__ float gumbel_from_bits(uint32_t bits) {
  float f = __uint_as_float((bits >> 9) | 0x3f800000u) - 1.0f;
  float u = fmaxf(f, 1.17549435e-38f);
  float t = __log2f(u);
  float s = __log2f(-t);
  return fmaf(0.69314718f, s, -0.36651292f);
}

// order-isomorphic u64 key: higher val wins; on equal val, LOWER idx wins
__device__ __forceinline__ unsigned long long pack_key(float val, int idx) {
  uint32_t fb = __float_as_uint(val);
  uint32_t key = (fb & 0x80000000u) ? ~fb : (fb | 0x80000000u);
  return ((unsigned long long)key << 32) |
         (unsigned long long)(0xFFFFFFFFu - (uint32_t)idx);
}

// ---------------- K1: LayerNorm + Q projection -> split bf16 (q*0.125) ----------------
__global__ __launch_bounds__(256, 4) void ln_qproj_kernel(
                                const float* __restrict__ queries,
                                const float* __restrict__ Wq,
                                const float* __restrict__ ln_g,
                                const float* __restrict__ ln_b,
                                ushort* __restrict__ qh_ws,
                                ushort* __restrict__ ql_ws) {
  __shared__ float xnT[QD][4];
  const int tid = threadIdx.x;
  const int wave = tid >> 6, lane = tid & 63;
  const int r0 = blockIdx.x * 4;
  const int r = r0 + wave;

  float vals[8];
  float s = 0.f;
#pragma unroll
  for (int j = 0; j < 8; ++j) { vals[j] = queries[r * QD + j * 64 + lane]; s += vals[j]; }
#pragma unroll
  for (int m = 32; m >= 1; m >>= 1) s += __shfl_xor(s, m, 64);
  const float mu = s * (1.f / 512.f);
  float ss = 0.f;
#pragma unroll
  for (int j = 0; j < 8; ++j) { float d = vals[j] - mu; ss += d * d; }
#pragma unroll
  for (int m = 32; m >= 1; m >>= 1) ss += __shfl_xor(ss, m, 64);
  const float rstd = 1.f / sqrtf(ss * (1.f / 512.f) + 1e-5f);
#pragma unroll
  for (int j = 0; j < 8; ++j) {
    int e = j * 64 + lane;
    xnT[e][wave] = (vals[j] - mu) * rstd * ln_g[e] + ln_b[e];
  }
  __syncthreads();

  const int e = blockIdx.y * 256 + tid;
  float a0 = 0.f, a1 = 0.f, a2 = 0.f, a3 = 0.f;
#pragma unroll 4
  for (int i = 0; i < QD; ++i) {
    f32x4 xv = *(const f32x4*)&xnT[i][0];
    float w = Wq[i * EMBD + e];
    a0 += xv.x * w; a1 += xv.y * w; a2 += xv.z * w; a3 += xv.w * w;
  }
  const int h = e >> 6, d = e & 63;
  float aa[4] = {a0, a1, a2, a3};
#pragma unroll
  for (int i = 0; i < 4; ++i) {
    float q = aa[i] * 0.125f;
    uint32_t hp = cvt_pk_bf16(q, q);
    float resid = q - __uint_as_float(hp << 16);
    uint32_t lp = cvt_pk_bf16(resid, resid);
    size_t off = ((size_t)h * 512 + (r0 + i)) * 64 + d;
    qh_ws[off] = (ushort)(hp & 0xFFFFu);
    ql_ws[off] = (ushort)(lp & 0xFFFFu);
  }
}

// ---------------- K2: k = glove @ Wk -> split bf16; XCD-grouped 1D grid ----------------
// id decode: lo=id&7, head=(id>>3)&7, vg=(id>>6)*8+lo. glove-tile sharers (fixed vg,
// all heads) have ids == lo (mod 8) within one 64-id window -> same XCD, same time.
#define BKk 60
__global__ __launch_bounds__(256, 4) void kproj_kernel(
                             const float* __restrict__ glove,
                             const float* __restrict__ Wk,
                             ushort* __restrict__ kh_ws,
                             ushort* __restrict__ kl_ws) {
  const int id = blockIdx.x;
  const int lo = id & 7, h = (id >> 3) & 7, vg = (id >> 6) * 8 + lo;
  if (vg >= 313) return;                 // padded grid tail (uniform exit)
  const int v0 = vg * 64;
  const int n0 = h * 64;
  __shared__ float AsT[BKk][68];
  __shared__ float Bs[BKk][64];
  const int tid = threadIdx.x;
  const int ty = tid >> 4, tx = tid & 15;
  f32x2 acc2[4][2] = {};
  for (int s = 0; s < 5; ++s) {
    const int w0 = s * BKk;
    __syncthreads();
    for (int f = tid; f < 64 * 15; f += 256) {
      int row = f / 15, c4 = f % 15;
      int v = v0 + row;
      float4 g4 = (v < VOCAB) ? *(const float4*)&glove[(size_t)v * WDn + w0 + c4 * 4]
                              : make_float4(0.f, 0.f, 0.f, 0.f);
      AsT[c4 * 4 + 0][row] = g4.x;
      AsT[c4 * 4 + 1][row] = g4.y;
      AsT[c4 * 4 + 2][row] = g4.z;
      AsT[c4 * 4 + 3][row] = g4.w;
    }
    for (int f = tid; f < BKk * 16; f += 256) {
      int row = f / 16, c4 = f % 16;
      *(float4*)&Bs[row][c4 * 4] = *(const float4*)&Wk[(size_t)(w0 + row) * EMBD + n0 + c4 * 4];
    }
    __syncthreads();
#pragma unroll 4
    for (int w = 0; w < BKk; ++w) {
      f32x4 aq = *(const f32x4*)&AsT[w][ty * 4];
      f32x4 bv = *(const f32x4*)&Bs[w][tx * 4];
      f32x2 bl = lo2(bv), bh = hi2(bv);
      f32x2 a01 = lo2(aq), a23 = hi2(aq);
      pk_fma_blo(acc2[0][0], a01, bl); pk_fma_blo(acc2[0][1], a01, bh);
      pk_fma_bhi(acc2[1][0], a01, bl); pk_fma_bhi(acc2[1][1], a01, bh);
      pk_fma_blo(acc2[2][0], a23, bl); pk_fma_blo(acc2[2][1], a23, bh);
      pk_fma_bhi(acc2[3][0], a23, bl); pk_fma_bhi(acc2[3][1], a23, bh);
    }
  }
#pragma unroll
  for (int i = 0; i < 4; ++i) {
    int v = v0 + ty * 4 + i;
    if (v < VOCAB) {
      f32x4 kv = {acc2[i][0].x, acc2[i][0].y, acc2[i][1].x, acc2[i][1].y};
      uint2 hi, lo2v;
      split4(kv, hi, lo2v);
      size_t off = ((size_t)h * VOCAB + v) * 64 + tx * 4;
      *(uint2*)&kh_ws[off] = hi;
      *(uint2*)&kl_ws[off] = lo2v;
    }
  }
}

// ---------------- K3: MFMA split-bf16 scores; 128x128 tile, 8 waves ----------------
template<bool FULL>
__device__ __forceinline__ void score_epi(const f32x4 (&acc)[8],
                                          int v0, int tx, int ty, int rowtile, int h,
                                          unsigned long long* __restrict__ pk_buf) {
#pragma unroll
  for (int i = 0; i < 4; ++i) {
    const int r = rowtile * 128 + ty * 4 + i;    // ty = tid>>4 in [0,32): same per-wave C-layout
    const int b = r >> 7, q = r & 127;
    const int rowidx = (b * NH + h) * NQn + q;
    const uint32_t base = (uint32_t)rowidx * (uint32_t)VOCAB;

    uint32_t x0[8], x1[8];
#pragma unroll
    for (int j = 0; j < 8; ++j) {
      x0[j] = 0u;
      x1[j] = base + (uint32_t)(v0 + tx + 16 * j);
    }
    tf8(x0, x1);

    float best = -INFINITY; int bidx = 0x7fffffff;
#pragma unroll
    for (int j = 0; j < 8; ++j) {
      int v = v0 + tx + 16 * j;
      if (FULL || v < VOCAB) {
        float g = gumbel_from_bits(x0[j] ^ x1[j]);
        float val = acc[j][i] - g;
        if (val > best) { best = val; bidx = v; }
      }
    }
#pragma unroll
    for (int m = 8; m >= 1; m >>= 1) {
      float ov = __shfl_xor(best, m, 64);
      int   oi = __shfl_xor(bidx, m, 64);
      if (ov > best || (ov == best && oi < bidx)) { best = ov; bidx = oi; }
    }
    if (tx == 0) atomicMax(&pk_buf[rowidx], pack_key(best, bidx));
  }
}

// 128 rows x 128 cols per block, 512 threads (8 waves). LDS = swizzled Kh|Kl 32 KB
// -> 4 blocks/CU = 32 waves. id decode: head=id&7, rowtile=(id>>3)&3, chunk=id>>5;
// K-tile sharers (fixed chunk,head) are == head (mod 8) within a 32-id window.
__global__ __launch_bounds__(512, 8) void score_kernel(
                  const ushort* __restrict__ qh_ws,
                  const ushort* __restrict__ ql_ws,
                  const ushort* __restrict__ kh_ws,
                  const ushort* __restrict__ kl_ws,
                  unsigned long long* __restrict__ pk_buf) {
  __shared__ uint4 lds4[2048];         // 32 KB
  char* const Kh = (char*)lds4;        // 16 KB [128][128B] swizzled
  char* const Kl = Kh + 16384;         // 16 KB
  const int tid = threadIdx.x;
  const int id = blockIdx.x;
  const int h = id & 7, rowtile = (id >> 3) & 3, chunk = id >> 5;
  const int v0 = chunk * VCHUNK;
  const int tx = tid & 15, ty = tid >> 4;
  const int w = tid >> 6;              // wave id [0,8): rows rowtile*128 + w*16 ..
  const int g4 = (tid >> 4) & 3;       // k-group
  const int swz = (tx & 7) << 4;

  // A fragments from global (private per lane)
  bf16x8 aH[2], aL[2];
  {
    const size_t qbase = ((size_t)h * 512 + rowtile * 128 + w * 16 + tx) * 64 + g4 * 8;
#pragma unroll
    for (int kh = 0; kh < 2; ++kh) {
      aH[kh] = *(const bf16x8*)(qh_ws + qbase + kh * 32);
      aL[kh] = *(const bf16x8*)(ql_ws + qbase + kh * 32);
    }
  }

  // stage K tile (swizzled ds_write), 512 threads -> 2 iters
  for (int f = tid; f < 128 * 8; f += 512) {
    int row = f >> 3, c8 = f & 7;
    int v = v0 + row;
    uint4 vh = {0u, 0u, 0u, 0u}, vl = {0u, 0u, 0u, 0u};
    if (v < VOCAB) {
      size_t off = ((size_t)h * VOCAB + v) * 64 + c8 * 8;
      vh = *(const uint4*)(kh_ws + off);
      vl = *(const uint4*)(kl_ws + off);
    }
    int loff = (row * 128 + c8 * 16) ^ ((row & 7) << 4);
    *(uint4*)(Kh + loff) = vh;
    *(uint4*)(Kl + loff) = vl;
  }
  __syncthreads();

  f32x4 acc[8] = {};
#pragma unroll
  for (int ct = 0; ct < 8; ++ct) {
    const int bbase = (ct * 16 + tx) * 128 + g4 * 16;
    bf16x8 bH[2], bL[2];
#pragma unroll
    for (int kh = 0; kh < 2; ++kh) {
      int off = (bbase + kh * 64) ^ swz;
      bH[kh] = *(const bf16x8*)(Kh + off);
      bL[kh] = *(const bf16x8*)(Kl + off);
    }
    acc[ct] = __builtin_amdgcn_mfma_f32_16x16x32_bf16(aH[0], bH[0], acc[ct], 0, 0, 0);
    acc[ct] = __builtin_amdgcn_mfma_f32_16x16x32_bf16(aH[1], bH[1], acc[ct], 0, 0, 0);
    acc[ct] = __builtin_amdgcn_mfma_f32_16x16x32_bf16(aH[0], bL[0], acc[ct], 0, 0, 0);
    acc[ct] = __builtin_amdgcn_mfma_f32_16x16x32_bf16(aH[1], bL[1], acc[ct], 0, 0, 0);
    acc[ct] = __builtin_amdgcn_mfma_f32_16x16x32_bf16(aL[0], bH[0], acc[ct], 0, 0, 0);
    acc[ct] = __builtin_amdgcn_mfma_f32_16x16x32_bf16(aL[1], bH[1], acc[ct], 0, 0, 0);
    acc[ct] = __builtin_amdgcn_mfma_f32_16x16x32_bf16(aL[0], bL[0], acc[ct], 0, 0, 0);
    acc[ct] = __builtin_amdgcn_mfma_f32_16x16x32_bf16(aL[1], bL[1], acc[ct], 0, 0, 0);
  }

  if (v0 + VCHUNK <= VOCAB)
    score_epi<true>(acc, v0, tx, ty, rowtile, h, pk_buf);
  else
    score_epi<false>(acc, v0, tx, ty, rowtile, h, pk_buf);
}

// ---------------- K5: gather + V proj + out proj + residual; 1 row/block ----------------
__global__ __launch_bounds__(512, 8) void out_kernel(
                           const float* __restrict__ queries,
                           const float* __restrict__ glove,
                           const float* __restrict__ Wv,
                           const float* __restrict__ Wout,
                           const float* __restrict__ b_out,
                           const unsigned long long* __restrict__ pk_buf,
                           float* __restrict__ out) {
  __shared__ float gl[NH][WDn];   // 9600 B
  __shared__ float vrow[EMBD];    // 2048 B
  __shared__ int idxs[NH];
  const int tid = threadIdx.x;
  const int r = blockIdx.x, b = r >> 7, q = r & 127;
  if (tid < NH) {
    unsigned long long p = pk_buf[(b * NH + tid) * NQn + q];
    idxs[tid] = (int)(0xFFFFFFFFu - (uint32_t)(p & 0xFFFFFFFFull));
  }
  __syncthreads();
  for (int f = tid; f < NH * 75; f += 512) {
    int hh = f / 75, c4 = f % 75;
    *(float4*)&gl[hh][c4 * 4] = *(const float4*)&glove[(size_t)idxs[hh] * WDn + c4 * 4];
  }
  __syncthreads();
  {
    const int e = tid, hh = e >> 6;
    float a = 0.f;
    for (int w = 0; w < WDn; ++w) a += gl[hh][w] * Wv[(size_t)w * EMBD + e];
    vrow[e] = a;
  }
  __syncthreads();
  {
    const int j = tid;
    float o = 0.f;
    for (int e = 0; e < EMBD; ++e) o += vrow[e] * Wout[(size_t)e * QD + j];
    out[(size_t)r * QD + j] = queries[(size_t)r * QD + j] + o + b_out[j];
  }
}

extern "C" void kernel_launch(void* const* d_in, const int* in_sizes, int n_in,
                              void* d_out, int out_size, void* d_ws, size_t ws_size,
                              hipStream_t stream) {
  const float* queries = (const float*)d_in[0];
  const float* glove   = (const float*)d_in[1];
  const float* Wq      = (const float*)d_in[2];
  const float* Wk      = (const float*)d_in[3];
  const float* Wv      = (const float*)d_in[4];
  const float* Wout    = (const float*)d_in[5];
  const float* b_out   = (const float*)d_in[6];
  const float* ln_g    = (const float*)d_in[7];
  const float* ln_b    = (const float*)d_in[8];
  float* out = (float*)d_out;

  // ws layout: qh | ql | kh | kl | pk_buf
  char* ws = (char*)d_ws;
  ushort* qh_ws = (ushort*)ws;
  ushort* ql_ws = qh_ws + (size_t)NH * 512 * 64;
  ushort* kh_ws = ql_ws + (size_t)NH * 512 * 64;
  ushort* kl_ws = kh_ws + (size_t)NH * VOCAB * 64;
  unsigned long long* pk_buf = (unsigned long long*)(kl_ws + (size_t)NH * VOCAB * 64);

  hipMemsetAsync(pk_buf, 0, (size_t)NB * NH * NQn * sizeof(unsigned long long), stream);

  hipLaunchKernelGGL(ln_qproj_kernel, dim3(128, 2), dim3(256), 0, stream,
                     queries, Wq, ln_g, ln_b, qh_ws, ql_ws);
  hipLaunchKernelGGL(kproj_kernel, dim3(2560), dim3(256), 0, stream,
                     glove, Wk, kh_ws, kl_ws);   // padded; vg>=313 blocks exit
  hipLaunchKernelGGL(score_kernel, dim3(5024), dim3(512), 0, stream,
                     qh_ws, ql_ws, kh_ws, kl_ws, pk_buf);
  hipLaunchKernelGGL(out_kernel, dim3(512), dim3(512), 0, stream,
                     queries, glove, Wv, Wout, b_out, pk_buf, out);
}

// Round 15
// 316.768 us; speedup vs baseline: 2.0018x; 1.0946x over previous
//
#include <hip/hip_runtime.h>
#include <cstdint>
#include <cmath>

#define NB 4
#define NQn 128
#define QD 512
#define EMBD 512
#define NH 8
#define DHn 64
#define VOCAB 20000
#define WDn 300
#define VCHUNK 128
#define NCHUNK 157   // ceil(20000/128)

typedef float f32x4 __attribute__((ext_vector_type(4)));
typedef float f32x2 __attribute__((ext_vector_type(2)));
typedef short bf16x8 __attribute__((ext_vector_type(8)));

__device__ __forceinline__ f32x2 lo2(f32x4 v) { return __builtin_shufflevector(v, v, 0, 1); }
__device__ __forceinline__ f32x2 hi2(f32x4 v) { return __builtin_shufflevector(v, v, 2, 3); }

__device__ __forceinline__ void pk_fma_blo(f32x2 &d, f32x2 a, f32x2 b) {
  asm("v_pk_fma_f32 %0, %1, %2, %0 op_sel:[0,0,0] op_sel_hi:[0,1,1]"
      : "+v"(d) : "v"(a), "v"(b));
}
__device__ __forceinline__ void pk_fma_bhi(f32x2 &d, f32x2 a, f32x2 b) {
  asm("v_pk_fma_f32 %0, %1, %2, %0 op_sel:[1,0,0] op_sel_hi:[1,1,1]"
      : "+v"(d) : "v"(a), "v"(b));
}

__device__ __forceinline__ uint32_t rotl(uint32_t x, int r) {
  return __builtin_amdgcn_alignbit(x, x, 32 - r);
}

__device__ __forceinline__ uint32_t cvt_pk_bf16(float a, float b) {
  uint32_t r;
  asm("v_cvt_pk_bf16_f32 %0, %1, %2" : "=v"(r) : "v"(a), "v"(b));
  return r;
}

// split f32x4 -> bf16 hi (RNE) + bf16 residual (verified R12/R13)
__device__ __forceinline__ void split4(f32x4 v, uint2 &hi, uint2 &lo) {
  uint32_t h01 = cvt_pk_bf16(v.x, v.y);
  uint32_t h23 = cvt_pk_bf16(v.z, v.w);
  float rx = v.x - __uint_as_float(h01 << 16);
  float ry = v.y - __uint_as_float(h01 & 0xFFFF0000u);
  float rz = v.z - __uint_as_float(h23 << 16);
  float rw = v.w - __uint_as_float(h23 & 0xFFFF0000u);
  hi = make_uint2(h01, h23);
  lo = make_uint2(cvt_pk_bf16(rx, ry), cvt_pk_bf16(rz, rw));
}

// 8 interleaved threefry2x32 chains (key=(0,42)); bits = out0 ^ out1 (verified R1)
#define TFK1 42u
#define TFK2 (0x1BD11BDAu ^ 42u)
__device__ __forceinline__ void tf8(uint32_t (&x0)[8], uint32_t (&x1)[8]) {
#define R8(r) \
  { _Pragma("unroll") for (int j = 0; j < 8; ++j) { x0[j] += x1[j]; x1[j] = rotl(x1[j], r); x1[j] ^= x0[j]; } }
#define K8(a, b) \
  { _Pragma("unroll") for (int j = 0; j < 8; ++j) { x0[j] += (a); x1[j] += (b); } }
  K8(0u, TFK1)
  R8(13) R8(15) R8(26) R8(6)  K8(TFK1, TFK2 + 1u)
  R8(17) R8(29) R8(16) R8(24) K8(TFK2, 0u + 2u)
  R8(13) R8(15) R8(26) R8(6)  K8(0u, TFK1 + 3u)
  R8(17) R8(29) R8(16) R8(24) K8(TFK1, TFK2 + 4u)
  R8(13) R8(15) R8(26) R8(6)  K8(TFK2, 0u + 5u)
#undef R8
#undef K8
}

// order-isomorphic u64 key: higher val wins; on equal val, LOWER idx wins
__device__ __forceinline__ unsigned long long pack_key(float val, int idx) {
  uint32_t fb = __float_as_uint(val);
  uint32_t key = (fb & 0x80000000u) ? ~fb : (fb | 0x80000000u);
  return ((unsigned long long)key << 32) |
         (unsigned long long)(0xFFFFFFFFu - (uint32_t)idx);
}

// ---------------- K1 (fused): kproj | ln_qproj | pk_buf zero ----------------
// block ids: [0,2560) kproj (XCD-grouped decode), [2560,2816) lnq, 2816 zero.
#define BKk 60
__global__ __launch_bounds__(256, 4) void prep_kernel(
                             const float* __restrict__ queries,
                             const float* __restrict__ Wq,
                             const float* __restrict__ ln_g,
                             const float* __restrict__ ln_b,
                             const float* __restrict__ glove,
                             const float* __restrict__ Wk,
                             ushort* __restrict__ qh_ws,
                             ushort* __restrict__ ql_ws,
                             ushort* __restrict__ kh_ws,
                             ushort* __restrict__ kl_ws,
                             unsigned long long* __restrict__ pk_buf) {
  __shared__ __align__(16) char smem[31680];
  const int bid = blockIdx.x;
  const int tid = threadIdx.x;

  if (bid < 2560) {
    // ---- kproj: k = glove @ Wk -> split bf16 hi/lo ----
    const int lo = bid & 7, h = (bid >> 3) & 7, vg = (bid >> 6) * 8 + lo;
    if (vg >= 313) return;
    const int v0 = vg * 64;
    const int n0 = h * 64;
    float (*AsT)[68] = (float(*)[68])smem;                // 16320 B
    float (*Bs)[64]  = (float(*)[64])(smem + 16320);      // 15360 B
    const int ty = tid >> 4, tx = tid & 15;
    f32x2 acc2[4][2] = {};
    for (int s = 0; s < 5; ++s) {
      const int w0 = s * BKk;
      __syncthreads();
      for (int f = tid; f < 64 * 15; f += 256) {
        int row = f / 15, c4 = f % 15;
        int v = v0 + row;
        float4 g4 = (v < VOCAB) ? *(const float4*)&glove[(size_t)v * WDn + w0 + c4 * 4]
                                : make_float4(0.f, 0.f, 0.f, 0.f);
        AsT[c4 * 4 + 0][row] = g4.x;
        AsT[c4 * 4 + 1][row] = g4.y;
        AsT[c4 * 4 + 2][row] = g4.z;
        AsT[c4 * 4 + 3][row] = g4.w;
      }
      for (int f = tid; f < BKk * 16; f += 256) {
        int row = f / 16, c4 = f % 16;
        *(float4*)&Bs[row][c4 * 4] = *(const float4*)&Wk[(size_t)(w0 + row) * EMBD + n0 + c4 * 4];
      }
      __syncthreads();
#pragma unroll 4
      for (int w = 0; w < BKk; ++w) {
        f32x4 aq = *(const f32x4*)&AsT[w][ty * 4];
        f32x4 bv = *(const f32x4*)&Bs[w][tx * 4];
        f32x2 bl = lo2(bv), bh = hi2(bv);
        f32x2 a01 = lo2(aq), a23 = hi2(aq);
        pk_fma_blo(acc2[0][0], a01, bl); pk_fma_blo(acc2[0][1], a01, bh);
        pk_fma_bhi(acc2[1][0], a01, bl); pk_fma_bhi(acc2[1][1], a01, bh);
        pk_fma_blo(acc2[2][0], a23, bl); pk_fma_blo(acc2[2][1], a23, bh);
        pk_fma_bhi(acc2[3][0], a23, bl); pk_fma_bhi(acc2[3][1], a23, bh);
      }
    }
#pragma unroll
    for (int i = 0; i < 4; ++i) {
      int v = v0 + ty * 4 + i;
      if (v < VOCAB) {
        f32x4 kv = {acc2[i][0].x, acc2[i][0].y, acc2[i][1].x, acc2[i][1].y};
        uint2 hi, lov;
        split4(kv, hi, lov);
        size_t off = ((size_t)h * VOCAB + v) * 64 + tx * 4;
        *(uint2*)&kh_ws[off] = hi;
        *(uint2*)&kl_ws[off] = lov;
      }
    }
  } else if (bid < 2816) {
    // ---- ln_qproj -> split bf16 of q*0.125 ----
    const int id = bid - 2560;           // 0..255: x = id&127 (row group), y = id>>7
    const int bx = id & 127, by = id >> 7;
    float (*xnT)[4] = (float(*)[4])smem; // 8192 B
    const int wave = tid >> 6, lane = tid & 63;
    const int r0 = bx * 4;
    const int r = r0 + wave;

    float vals[8];
    float s = 0.f;
#pragma unroll
    for (int j = 0; j < 8; ++j) { vals[j] = queries[r * QD + j * 64 + lane]; s += vals[j]; }
#pragma unroll
    for (int m = 32; m >= 1; m >>= 1) s += __shfl_xor(s, m, 64);
    const float mu = s * (1.f / 512.f);
    float ss = 0.f;
#pragma unroll
    for (int j = 0; j < 8; ++j) { float d = vals[j] - mu; ss += d * d; }
#pragma unroll
    for (int m = 32; m >= 1; m >>= 1) ss += __shfl_xor(ss, m, 64);
    const float rstd = 1.f / sqrtf(ss * (1.f / 512.f) + 1e-5f);
#pragma unroll
    for (int j = 0; j < 8; ++j) {
      int e = j * 64 + lane;
      xnT[e][wave] = (vals[j] - mu) * rstd * ln_g[e] + ln_b[e];
    }
    __syncthreads();

    const int e = by * 256 + tid;
    float a0 = 0.f, a1 = 0.f, a2 = 0.f, a3 = 0.f;
#pragma unroll 4
    for (int i = 0; i < QD; ++i) {
      f32x4 xv = *(const f32x4*)&xnT[i][0];
      float w = Wq[i * EMBD + e];
      a0 += xv.x * w; a1 += xv.y * w; a2 += xv.z * w; a3 += xv.w * w;
    }
    const int h = e >> 6, d = e & 63;
    float aa[4] = {a0, a1, a2, a3};
#pragma unroll
    for (int i = 0; i < 4; ++i) {
      float q = aa[i] * 0.125f;
      uint32_t hp = cvt_pk_bf16(q, q);
      float resid = q - __uint_as_float(hp << 16);
      uint32_t lp = cvt_pk_bf16(resid, resid);
      size_t off = ((size_t)h * 512 + (r0 + i)) * 64 + d;
      qh_ws[off] = (ushort)(hp & 0xFFFFu);
      ql_ws[off] = (ushort)(lp & 0xFFFFu);
    }
  } else {
    // ---- zero pk_buf (4096 u64) ----
    for (int f = tid; f < NB * NH * NQn; f += 256) pk_buf[f] = 0ull;
  }
}

// ---------------- K3: MFMA split-bf16 scores; 128x128 tile, 8 waves ----------------
template<bool FULL>
__device__ __forceinline__ void score_epi(const f32x4 (&acc)[8],
                                          int v0, int tx, int ty, int rowtile, int h,
                                          unsigned long long* __restrict__ pk_buf) {
#pragma unroll
  for (int i = 0; i < 4; ++i) {
    const int r = rowtile * 128 + ty * 4 + i;
    const int b = r >> 7, q = r & 127;
    const int rowidx = (b * NH + h) * NQn + q;
    const uint32_t base = (uint32_t)rowidx * (uint32_t)VOCAB;

    uint32_t x0[8], x1[8];
#pragma unroll
    for (int j = 0; j < 8; ++j) {
      x0[j] = 0u;
      x1[j] = base + (uint32_t)(v0 + tx + 16 * j);
    }
    tf8(x0, x1);

    float best = -INFINITY; int bidx = 0x7fffffff;
#pragma unroll
    for (int j = 0; j < 8; ++j) {
      int v = v0 + tx + 16 * j;
      if (FULL || v < VOCAB) {
        uint32_t bits = x0[j] ^ x1[j];
        float f = __uint_as_float((bits >> 9) | 0x3f800000u) - 1.0f;
        float u = fmaxf(f, 1.17549435e-38f);
        float t = __log2f(u);
        float s = __log2f(-t);
        // val = acc - ln2*s (+const dropped: uniform shift, argmax-invariant)
        float val = fmaf(-0.69314718f, s, acc[j][i]);
        if (val > best) { best = val; bidx = v; }
      }
    }
#pragma unroll
    for (int m = 8; m >= 1; m >>= 1) {
      float ov = __shfl_xor(best, m, 64);
      int   oi = __shfl_xor(bidx, m, 64);
      if (ov > best || (ov == best && oi < bidx)) { best = ov; bidx = oi; }
    }
    if (tx == 0) atomicMax(&pk_buf[rowidx], pack_key(best, bidx));
  }
}

__global__ __launch_bounds__(512, 8) void score_kernel(
                  const ushort* __restrict__ qh_ws,
                  const ushort* __restrict__ ql_ws,
                  const ushort* __restrict__ kh_ws,
                  const ushort* __restrict__ kl_ws,
                  unsigned long long* __restrict__ pk_buf) {
  __shared__ uint4 lds4[2048];         // 32 KB
  char* const Kh = (char*)lds4;        // 16 KB [128][128B] swizzled
  char* const Kl = Kh + 16384;         // 16 KB
  const int tid = threadIdx.x;
  const int id = blockIdx.x;
  const int h = id & 7, rowtile = (id >> 3) & 3, chunk = id >> 5;
  const int v0 = chunk * VCHUNK;
  const int tx = tid & 15, ty = tid >> 4;
  const int w = tid >> 6;
  const int g4 = (tid >> 4) & 3;
  const int swz = (tx & 7) << 4;

  // stage K tile (swizzled ds_write), 512 threads -> 2 iters
  for (int f = tid; f < 128 * 8; f += 512) {
    int row = f >> 3, c8 = f & 7;
    int v = v0 + row;
    uint4 vh = {0u, 0u, 0u, 0u}, vl = {0u, 0u, 0u, 0u};
    if (v < VOCAB) {
      size_t off = ((size_t)h * VOCAB + v) * 64 + c8 * 8;
      vh = *(const uint4*)(kh_ws + off);
      vl = *(const uint4*)(kl_ws + off);
    }
    int loff = (row * 128 + c8 * 16) ^ ((row & 7) << 4);
    *(uint4*)(Kh + loff) = vh;
    *(uint4*)(Kl + loff) = vl;
  }

  // A fragments from global (private per lane; issued alongside staging)
  bf16x8 aH[2], aL[2];
  {
    const size_t qbase = ((size_t)h * 512 + rowtile * 128 + w * 16 + tx) * 64 + g4 * 8;
#pragma unroll
    for (int kh = 0; kh < 2; ++kh) {
      aH[kh] = *(const bf16x8*)(qh_ws + qbase + kh * 32);
      aL[kh] = *(const bf16x8*)(ql_ws + qbase + kh * 32);
    }
  }
  __syncthreads();

  f32x4 acc[8] = {};
#pragma unroll
  for (int ct = 0; ct < 8; ++ct) {
    const int bbase = (ct * 16 + tx) * 128 + g4 * 16;
    bf16x8 bH[2], bL[2];
#pragma unroll
    for (int kh = 0; kh < 2; ++kh) {
      int off = (bbase + kh * 64) ^ swz;
      bH[kh] = *(const bf16x8*)(Kh + off);
      bL[kh] = *(const bf16x8*)(Kl + off);
    }
    acc[ct] = __builtin_amdgcn_mfma_f32_16x16x32_bf16(aH[0], bH[0], acc[ct], 0, 0, 0);
    acc[ct] = __builtin_amdgcn_mfma_f32_16x16x32_bf16(aH[1], bH[1], acc[ct], 0, 0, 0);
    acc[ct] = __builtin_amdgcn_mfma_f32_16x16x32_bf16(aH[0], bL[0], acc[ct], 0, 0, 0);
    acc[ct] = __builtin_amdgcn_mfma_f32_16x16x32_bf16(aH[1], bL[1], acc[ct], 0, 0, 0);
    acc[ct] = __builtin_amdgcn_mfma_f32_16x16x32_bf16(aL[0], bH[0], acc[ct], 0, 0, 0);
    acc[ct] = __builtin_amdgcn_mfma_f32_16x16x32_bf16(aL[1], bH[1], acc[ct], 0, 0, 0);
    acc[ct] = __builtin_amdgcn_mfma_f32_16x16x32_bf16(aL[0], bL[0], acc[ct], 0, 0, 0);
    acc[ct] = __builtin_amdgcn_mfma_f32_16x16x32_bf16(aL[1], bL[1], acc[ct], 0, 0, 0);
  }

  if (v0 + VCHUNK <= VOCAB)
    score_epi<true>(acc, v0, tx, ty, rowtile, h, pk_buf);
  else
    score_epi<false>(acc, v0, tx, ty, rowtile, h, pk_buf);
}

// ---------------- K5: gather + V proj + out proj + residual; 1 row/block ----------------
__global__ __launch_bounds__(512, 8) void out_kernel(
                           const float* __restrict__ queries,
                           const float* __restrict__ glove,
                           const float* __restrict__ Wv,
                           const float* __restrict__ Wout,
                           const float* __restrict__ b_out,
                           const unsigned long long* __restrict__ pk_buf,
                           float* __restrict__ out) {
  __shared__ float gl[NH][WDn];
  __shared__ float vrow[EMBD];
  __shared__ int idxs[NH];
  const int tid = threadIdx.x;
  const int r = blockIdx.x, b = r >> 7, q = r & 127;
  if (tid < NH) {
    unsigned long long p = pk_buf[(b * NH + tid) * NQn + q];
    idxs[tid] = (int)(0xFFFFFFFFu - (uint32_t)(p & 0xFFFFFFFFull));
  }
  __syncthreads();
  for (int f = tid; f < NH * 75; f += 512) {
    int hh = f / 75, c4 = f % 75;
    *(float4*)&gl[hh][c4 * 4] = *(const float4*)&glove[(size_t)idxs[hh] * WDn + c4 * 4];
  }
  __syncthreads();
  {
    const int e = tid, hh = e >> 6;
    float a = 0.f;
    for (int w = 0; w < WDn; ++w) a += gl[hh][w] * Wv[(size_t)w * EMBD + e];
    vrow[e] = a;
  }
  __syncthreads();
  {
    const int j = tid;
    float o = 0.f;
    for (int e = 0; e < EMBD; ++e) o += vrow[e] * Wout[(size_t)e * QD + j];
    out[(size_t)r * QD + j] = queries[(size_t)r * QD + j] + o + b_out[j];
  }
}

extern "C" void kernel_launch(void* const* d_in, const int* in_sizes, int n_in,
                              void* d_out, int out_size, void* d_ws, size_t ws_size,
                              hipStream_t stream) {
  const float* queries = (const float*)d_in[0];
  const float* glove   = (const float*)d_in[1];
  const float* Wq      = (const float*)d_in[2];
  const float* Wk      = (const float*)d_in[3];
  const float* Wv      = (const float*)d_in[4];
  const float* Wout    = (const float*)d_in[5];
  const float* b_out   = (const float*)d_in[6];
  const float* ln_g    = (const float*)d_in[7];
  const float* ln_b    = (const float*)d_in[8];
  float* out = (float*)d_out;

  // ws layout: qh | ql | kh | kl | pk_buf
  char* ws = (char*)d_ws;
  ushort* qh_ws = (ushort*)ws;
  ushort* ql_ws = qh_ws + (size_t)NH * 512 * 64;
  ushort* kh_ws = ql_ws + (size_t)NH * 512 * 64;
  ushort* kl_ws = kh_ws + (size_t)NH * VOCAB * 64;
  unsigned long long* pk_buf = (unsigned long long*)(kl_ws + (size_t)NH * VOCAB * 64);

  hipLaunchKernelGGL(prep_kernel, dim3(2817), dim3(256), 0, stream,
                     queries, Wq, ln_g, ln_b, glove, Wk,
                     qh_ws, ql_ws, kh_ws, kl_ws, pk_buf);
  hipLaunchKernelGGL(score_kernel, dim3(5024), dim3(512), 0, stream,
                     qh_ws, ql_ws, kh_ws, kl_ws, pk_buf);
  hipLaunchKernelGGL(out_kernel, dim3(512), dim3(512), 0, stream,
                     queries, glove, Wv, Wout, b_out, pk_buf, out);
}

// Round 17
// 304.602 us; speedup vs baseline: 2.0817x; 1.0399x over previous
//
#include <hip/hip_runtime.h>
#include <cstdint>
#include <cmath>

#define NB 4
#define NQn 128
#define QD 512
#define EMBD 512
#define NH 8
#define DHn 64
#define VOCAB 20000
#define WDn 300
#define VCHUNK 128
#define NCHUNK 157   // ceil(20000/128)

typedef float f32x4 __attribute__((ext_vector_type(4)));
typedef short bf16x8 __attribute__((ext_vector_type(8)));

__device__ __forceinline__ uint32_t rotl(uint32_t x, int r) {
  return __builtin_amdgcn_alignbit(x, x, 32 - r);
}

__device__ __forceinline__ uint32_t cvt_pk_bf16(float a, float b) {
  uint32_t r;
  asm("v_cvt_pk_bf16_f32 %0, %1, %2" : "=v"(r) : "v"(a), "v"(b));
  return r;
}

// split f32x4 -> bf16 hi (RNE) + bf16 residual (verified R12/R13)
__device__ __forceinline__ void split4(f32x4 v, uint2 &hi, uint2 &lo) {
  uint32_t h01 = cvt_pk_bf16(v.x, v.y);
  uint32_t h23 = cvt_pk_bf16(v.z, v.w);
  float rx = v.x - __uint_as_float(h01 << 16);
  float ry = v.y - __uint_as_float(h01 & 0xFFFF0000u);
  float rz = v.z - __uint_as_float(h23 << 16);
  float rw = v.w - __uint_as_float(h23 & 0xFFFF0000u);
  hi = make_uint2(h01, h23);
  lo = make_uint2(cvt_pk_bf16(rx, ry), cvt_pk_bf16(rz, rw));
}

// 8 interleaved threefry2x32 chains (key=(0,42)); bits = out0 ^ out1 (verified R1)
#define TFK1 42u
#define TFK2 (0x1BD11BDAu ^ 42u)
__device__ __forceinline__ void tf8(uint32_t (&x0)[8], uint32_t (&x1)[8]) {
#define R8(r) \
  { _Pragma("unroll") for (int j = 0; j < 8; ++j) { x0[j] += x1[j]; x1[j] = rotl(x1[j], r); x1[j] ^= x0[j]; } }
#define K8(a, b) \
  { _Pragma("unroll") for (int j = 0; j < 8; ++j) { x0[j] += (a); x1[j] += (b); } }
  K8(0u, TFK1)
  R8(13) R8(15) R8(26) R8(6)  K8(TFK1, TFK2 + 1u)
  R8(17) R8(29) R8(16) R8(24) K8(TFK2, 0u + 2u)
  R8(13) R8(15) R8(26) R8(6)  K8(0u, TFK1 + 3u)
  R8(17) R8(29) R8(16) R8(24) K8(TFK1, TFK2 + 4u)
  R8(13) R8(15) R8(26) R8(6)  K8(TFK2, 0u + 5u)
#undef R8
#undef K8
}

// order-isomorphic u64 key: higher val wins; on equal val, LOWER idx wins
__device__ __forceinline__ unsigned long long pack_key(float val, int idx) {
  uint32_t fb = __float_as_uint(val);
  uint32_t key = (fb & 0x80000000u) ? ~fb : (fb | 0x80000000u);
  return ((unsigned long long)key << 32) |
         (unsigned long long)(0xFFFFFFFFu - (uint32_t)idx);
}

// ---------------- K1 (fused): kproj(MFMA) | ln_qproj | pk_buf zero ----------------
// block ids: [0,2560) kproj (XCD-grouped decode), [2560,2816) lnq, 2816 zero.
__global__ __launch_bounds__(256, 4) void prep_kernel(
                             const float* __restrict__ queries,
                             const float* __restrict__ Wq,
                             const float* __restrict__ ln_g,
                             const float* __restrict__ ln_b,
                             const float* __restrict__ glove,
                             const float* __restrict__ Wk,
                             ushort* __restrict__ qh_ws,
                             ushort* __restrict__ ql_ws,
                             ushort* __restrict__ kh_ws,
                             ushort* __restrict__ kl_ws,
                             unsigned long long* __restrict__ pk_buf) {
  __shared__ __align__(16) char smem[32768];
  const int bid = blockIdx.x;
  const int tid = threadIdx.x;

  if (bid < 2560) {
    // ---- kproj via split-bf16 MFMA: k = glove @ Wk -> split bf16 hi/lo ----
    // 64 v-rows x 64 dims (one head) per block; K=300 zero-padded to 320.
    const int lo = bid & 7, h = (bid >> 3) & 7, vg = (bid >> 6) * 8 + lo;
    if (vg >= 313) return;
    const int v0 = vg * 64;
    const int n0 = h * 64;
    char* const Gh = smem;            // [64 rows][64 k]bf16, swizzled, 8 KB
    char* const Gl = smem + 8192;
    char* const Wh = smem + 16384;    // [64 cols][64 k]bf16, swizzled, 8 KB
    char* const Wl = smem + 24576;
    const int w = tid >> 6, lane = tid & 63;
    const int txl = lane & 15;
    const int g4 = (lane >> 4) & 3;
    const int swzA = (txl & 7) << 4;

    f32x4 acc[4] = {};   // 4 col-tiles of 16x16, C-layout verified (R12+)

    for (int s = 0; s < 5; ++s) {
      const int k0 = s * 64;
      __syncthreads();
      // stage glove 64 rows x 64 k (split bf16 hi/lo, swizzled)
      for (int f = tid; f < 64 * 16; f += 256) {
        int row = f >> 4, c4 = f & 15;
        int v = v0 + row, kk = k0 + c4 * 4;
        f32x4 g = {0.f, 0.f, 0.f, 0.f};
        if (v < VOCAB && kk + 4 <= WDn)
          g = *(const f32x4*)&glove[(size_t)v * WDn + kk];
        uint2 hi, lov;
        split4(g, hi, lov);
        int off = (row * 128 + c4 * 8) ^ ((row & 7) << 4);
        *(uint2*)(Gh + off) = hi;
        *(uint2*)(Gl + off) = lov;
      }
      // stage Wk transposed: [d][kk] (split bf16, swizzled); reads coalesced in d
      for (int f = tid; f < 64 * 16; f += 256) {
        int kk = f >> 4, d4 = f & 15;
        int kg = k0 + kk;
        f32x4 wv = {0.f, 0.f, 0.f, 0.f};
        if (kg < WDn)
          wv = *(const f32x4*)&Wk[(size_t)kg * EMBD + n0 + d4 * 4];
        uint2 hi, lov;
        split4(wv, hi, lov);
        ushort hs[4] = {(ushort)(hi.x & 0xFFFFu), (ushort)(hi.x >> 16),
                        (ushort)(hi.y & 0xFFFFu), (ushort)(hi.y >> 16)};
        ushort ls[4] = {(ushort)(lov.x & 0xFFFFu), (ushort)(lov.x >> 16),
                        (ushort)(lov.y & 0xFFFFu), (ushort)(lov.y >> 16)};
#pragma unroll
        for (int j = 0; j < 4; ++j) {
          int d = d4 * 4 + j;
          int off = (d * 128 + kk * 2) ^ ((d & 7) << 4);
          *(ushort*)(Wh + off) = hs[j];
          *(ushort*)(Wl + off) = ls[j];
        }
      }
      __syncthreads();

      // A fragments: row = w*16 + txl, k = g4*8 + kh*32 (same layout as score)
      bf16x8 aH[2], aL[2];
#pragma unroll
      for (int kh = 0; kh < 2; ++kh) {
        int off = ((w * 16 + txl) * 128 + (g4 * 8 + kh * 32) * 2) ^ swzA;
        aH[kh] = *(const bf16x8*)(Gh + off);
        aL[kh] = *(const bf16x8*)(Gl + off);
      }
#pragma unroll
      for (int ct = 0; ct < 4; ++ct) {
        bf16x8 bH[2], bL[2];
#pragma unroll
        for (int kh = 0; kh < 2; ++kh) {
          int off = ((ct * 16 + txl) * 128 + (g4 * 8 + kh * 32) * 2) ^ swzA;
          bH[kh] = *(const bf16x8*)(Wh + off);
          bL[kh] = *(const bf16x8*)(Wl + off);
        }
        acc[ct] = __builtin_amdgcn_mfma_f32_16x16x32_bf16(aH[0], bH[0], acc[ct], 0, 0, 0);
        acc[ct] = __builtin_amdgcn_mfma_f32_16x16x32_bf16(aH[1], bH[1], acc[ct], 0, 0, 0);
        acc[ct] = __builtin_amdgcn_mfma_f32_16x16x32_bf16(aH[0], bL[0], acc[ct], 0, 0, 0);
        acc[ct] = __builtin_amdgcn_mfma_f32_16x16x32_bf16(aH[1], bL[1], acc[ct], 0, 0, 0);
        acc[ct] = __builtin_amdgcn_mfma_f32_16x16x32_bf16(aL[0], bH[0], acc[ct], 0, 0, 0);
        acc[ct] = __builtin_amdgcn_mfma_f32_16x16x32_bf16(aL[1], bH[1], acc[ct], 0, 0, 0);
        acc[ct] = __builtin_amdgcn_mfma_f32_16x16x32_bf16(aL[0], bL[0], acc[ct], 0, 0, 0);
        acc[ct] = __builtin_amdgcn_mfma_f32_16x16x32_bf16(aL[1], bL[1], acc[ct], 0, 0, 0);
      }
    }

    // epilogue: C row = w*16 + (lane>>4)*4 + i, col = ct*16 + txl (verified layout)
#pragma unroll
    for (int ct = 0; ct < 4; ++ct) {
#pragma unroll
      for (int i = 0; i < 4; ++i) {
        int v = v0 + w * 16 + (lane >> 4) * 4 + i;
        if (v < VOCAB) {
          float x = acc[ct][i];
          uint32_t hp = cvt_pk_bf16(x, x);
          float resid = x - __uint_as_float(hp << 16);
          uint32_t lp = cvt_pk_bf16(resid, resid);
          size_t off = ((size_t)h * VOCAB + v) * 64 + ct * 16 + txl;
          kh_ws[off] = (ushort)(hp & 0xFFFFu);
          kl_ws[off] = (ushort)(lp & 0xFFFFu);
        }
      }
    }
  } else if (bid < 2816) {
    // ---- ln_qproj -> split bf16 of q*0.125 (byte-identical to R15) ----
    const int id = bid - 2560;
    const int bx = id & 127, by = id >> 7;
    float (*xnT)[4] = (float(*)[4])smem;
    const int wave = tid >> 6, lane = tid & 63;
    const int r0 = bx * 4;
    const int r = r0 + wave;

    float vals[8];
    float s = 0.f;
#pragma unroll
    for (int j = 0; j < 8; ++j) { vals[j] = queries[r * QD + j * 64 + lane]; s += vals[j]; }
#pragma unroll
    for (int m = 32; m >= 1; m >>= 1) s += __shfl_xor(s, m, 64);
    const float mu = s * (1.f / 512.f);
    float ss = 0.f;
#pragma unroll
    for (int j = 0; j < 8; ++j) { float d = vals[j] - mu; ss += d * d; }
#pragma unroll
    for (int m = 32; m >= 1; m >>= 1) ss += __shfl_xor(ss, m, 64);
    const float rstd = 1.f / sqrtf(ss * (1.f / 512.f) + 1e-5f);
#pragma unroll
    for (int j = 0; j < 8; ++j) {
      int e = j * 64 + lane;
      xnT[e][wave] = (vals[j] - mu) * rstd * ln_g[e] + ln_b[e];
    }
    __syncthreads();

    const int e = by * 256 + tid;
    float a0 = 0.f, a1 = 0.f, a2 = 0.f, a3 = 0.f;
#pragma unroll 4
    for (int i = 0; i < QD; ++i) {
      f32x4 xv = *(const f32x4*)&xnT[i][0];
      float w = Wq[i * EMBD + e];
      a0 += xv.x * w; a1 += xv.y * w; a2 += xv.z * w; a3 += xv.w * w;
    }
    const int h = e >> 6, d = e & 63;
    float aa[4] = {a0, a1, a2, a3};
#pragma unroll
    for (int i = 0; i < 4; ++i) {
      float q = aa[i] * 0.125f;
      uint32_t hp = cvt_pk_bf16(q, q);
      float resid = q - __uint_as_float(hp << 16);
      uint32_t lp = cvt_pk_bf16(resid, resid);
      size_t off = ((size_t)h * 512 + (r0 + i)) * 64 + d;
      qh_ws[off] = (ushort)(hp & 0xFFFFu);
      ql_ws[off] = (ushort)(lp & 0xFFFFu);
    }
  } else {
    // ---- zero pk_buf (4096 u64) ----
    for (int f = tid; f < NB * NH * NQn; f += 256) pk_buf[f] = 0ull;
  }
}

// ---------------- K3: MFMA split-bf16 scores (R15 verbatim) ----------------
template<bool FULL>
__device__ __forceinline__ void score_epi(const f32x4 (&acc)[8],
                                          int v0, int tx, int ty, int rowtile, int h,
                                          unsigned long long* __restrict__ pk_buf) {
#pragma unroll
  for (int i = 0; i < 4; ++i) {
    const int r = rowtile * 128 + ty * 4 + i;
    const int b = r >> 7, q = r & 127;
    const int rowidx = (b * NH + h) * NQn + q;
    const uint32_t base = (uint32_t)rowidx * (uint32_t)VOCAB;

    uint32_t x0[8], x1[8];
#pragma unroll
    for (int j = 0; j < 8; ++j) {
      x0[j] = 0u;
      x1[j] = base + (uint32_t)(v0 + tx + 16 * j);
    }
    tf8(x0, x1);

    float best = -INFINITY; int bidx = 0x7fffffff;
#pragma unroll
    for (int j = 0; j < 8; ++j) {
      int v = v0 + tx + 16 * j;
      if (FULL || v < VOCAB) {
        uint32_t bits = x0[j] ^ x1[j];
        float f = __uint_as_float((bits >> 9) | 0x3f800000u) - 1.0f;
        float u = fmaxf(f, 1.17549435e-38f);
        float t = __log2f(u);
        float s = __log2f(-t);
        float val = fmaf(-0.69314718f, s, acc[j][i]);   // uniform const dropped
        if (val > best) { best = val; bidx = v; }
      }
    }
#pragma unroll
    for (int m = 8; m >= 1; m >>= 1) {
      float ov = __shfl_xor(best, m, 64);
      int   oi = __shfl_xor(bidx, m, 64);
      if (ov > best || (ov == best && oi < bidx)) { best = ov; bidx = oi; }
    }
    if (tx == 0) atomicMax(&pk_buf[rowidx], pack_key(best, bidx));
  }
}

__global__ __launch_bounds__(512, 8) void score_kernel(
                  const ushort* __restrict__ qh_ws,
                  const ushort* __restrict__ ql_ws,
                  const ushort* __restrict__ kh_ws,
                  const ushort* __restrict__ kl_ws,
                  unsigned long long* __restrict__ pk_buf) {
  __shared__ uint4 lds4[2048];         // 32 KB
  char* const Kh = (char*)lds4;
  char* const Kl = Kh + 16384;
  const int tid = threadIdx.x;
  const int id = blockIdx.x;
  const int h = id & 7, rowtile = (id >> 3) & 3, chunk = id >> 5;
  const int v0 = chunk * VCHUNK;
  const int tx = tid & 15, ty = tid >> 4;
  const int w = tid >> 6;
  const int g4 = (tid >> 4) & 3;
  const int swz = (tx & 7) << 4;

  // stage K tile (swizzled ds_write)
  for (int f = tid; f < 128 * 8; f += 512) {
    int row = f >> 3, c8 = f & 7;
    int v = v0 + row;
    uint4 vh = {0u, 0u, 0u, 0u}, vl = {0u, 0u, 0u, 0u};
    if (v < VOCAB) {
      size_t off = ((size_t)h * VOCAB + v) * 64 + c8 * 8;
      vh = *(const uint4*)(kh_ws + off);
      vl = *(const uint4*)(kl_ws + off);
    }
    int loff = (row * 128 + c8 * 16) ^ ((row & 7) << 4);
    *(uint4*)(Kh + loff) = vh;
    *(uint4*)(Kl + loff) = vl;
  }

  // A fragments from global (private per lane)
  bf16x8 aH[2], aL[2];
  {
    const size_t qbase = ((size_t)h * 512 + rowtile * 128 + w * 16 + tx) * 64 + g4 * 8;
#pragma unroll
    for (int kh = 0; kh < 2; ++kh) {
      aH[kh] = *(const bf16x8*)(qh_ws + qbase + kh * 32);
      aL[kh] = *(const bf16x8*)(ql_ws + qbase + kh * 32);
    }
  }
  __syncthreads();

  f32x4 acc[8] = {};
#pragma unroll
  for (int ct = 0; ct < 8; ++ct) {
    const int bbase = (ct * 16 + tx) * 128 + g4 * 16;
    bf16x8 bH[2], bL[2];
#pragma unroll
    for (int kh = 0; kh < 2; ++kh) {
      int off = (bbase + kh * 64) ^ swz;
      bH[kh] = *(const bf16x8*)(Kh + off);
      bL[kh] = *(const bf16x8*)(Kl + off);
    }
    acc[ct] = __builtin_amdgcn_mfma_f32_16x16x32_bf16(aH[0], bH[0], acc[ct], 0, 0, 0);
    acc[ct] = __builtin_amdgcn_mfma_f32_16x16x32_bf16(aH[1], bH[1], acc[ct], 0, 0, 0);
    acc[ct] = __builtin_amdgcn_mfma_f32_16x16x32_bf16(aH[0], bL[0], acc[ct], 0, 0, 0);
    acc[ct] = __builtin_amdgcn_mfma_f32_16x16x32_bf16(aH[1], bL[1], acc[ct], 0, 0, 0);
    acc[ct] = __builtin_amdgcn_mfma_f32_16x16x32_bf16(aL[0], bH[0], acc[ct], 0, 0, 0);
    acc[ct] = __builtin_amdgcn_mfma_f32_16x16x32_bf16(aL[1], bH[1], acc[ct], 0, 0, 0);
    acc[ct] = __builtin_amdgcn_mfma_f32_16x16x32_bf16(aL[0], bL[0], acc[ct], 0, 0, 0);
    acc[ct] = __builtin_amdgcn_mfma_f32_16x16x32_bf16(aL[1], bL[1], acc[ct], 0, 0, 0);
  }

  if (v0 + VCHUNK <= VOCAB)
    score_epi<true>(acc, v0, tx, ty, rowtile, h, pk_buf);
  else
    score_epi<false>(acc, v0, tx, ty, rowtile, h, pk_buf);
}

// ---------------- K5: gather + V proj + out proj + residual (R15 verbatim) ----------------
__global__ __launch_bounds__(512, 8) void out_kernel(
                           const float* __restrict__ queries,
                           const float* __restrict__ glove,
                           const float* __restrict__ Wv,
                           const float* __restrict__ Wout,
                           const float* __restrict__ b_out,
                           const unsigned long long* __restrict__ pk_buf,
                           float* __restrict__ out) {
  __shared__ float gl[NH][WDn];
  __shared__ float vrow[EMBD];
  __shared__ int idxs[NH];
  const int tid = threadIdx.x;
  const int r = blockIdx.x, b = r >> 7, q = r & 127;
  if (tid < NH) {
    unsigned long long p = pk_buf[(b * NH + tid) * NQn + q];
    idxs[tid] = (int)(0xFFFFFFFFu - (uint32_t)(p & 0xFFFFFFFFull));
  }
  __syncthreads();
  for (int f = tid; f < NH * 75; f += 512) {
    int hh = f / 75, c4 = f % 75;
    *(float4*)&gl[hh][c4 * 4] = *(const float4*)&glove[(size_t)idxs[hh] * WDn + c4 * 4];
  }
  __syncthreads();
  {
    const int e = tid, hh = e >> 6;
    float a = 0.f;
    for (int w = 0; w < WDn; ++w) a += gl[hh][w] * Wv[(size_t)w * EMBD + e];
    vrow[e] = a;
  }
  __syncthreads();
  {
    const int j = tid;
    float o = 0.f;
    for (int e = 0; e < EMBD; ++e) o += vrow[e] * Wout[(size_t)e * QD + j];
    out[(size_t)r * QD + j] = queries[(size_t)r * QD + j] + o + b_out[j];
  }
}

extern "C" void kernel_launch(void* const* d_in, const int* in_sizes, int n_in,
                              void* d_out, int out_size, void* d_ws, size_t ws_size,
                              hipStream_t stream) {
  const float* queries = (const float*)d_in[0];
  const float* glove   = (const float*)d_in[1];
  const float* Wq      = (const float*)d_in[2];
  const float* Wk      = (const float*)d_in[3];
  const float* Wv      = (const float*)d_in[4];
  const float* Wout    = (const float*)d_in[5];
  const float* b_out   = (const float*)d_in[6];
  const float* ln_g    = (const float*)d_in[7];
  const float* ln_b    = (const float*)d_in[8];
  float* out = (float*)d_out;

  // ws layout: qh | ql | kh | kl | pk_buf
  char* ws = (char*)d_ws;
  ushort* qh_ws = (ushort*)ws;
  ushort* ql_ws = qh_ws + (size_t)NH * 512 * 64;
  ushort* kh_ws = ql_ws + (size_t)NH * 512 * 64;
  ushort* kl_ws = kh_ws + (size_t)NH * VOCAB * 64;
  unsigned long long* pk_buf = (unsigned long long*)(kl_ws + (size_t)NH * VOCAB * 64);

  hipLaunchKernelGGL(prep_kernel, dim3(2817), dim3(256), 0, stream,
                     queries, Wq, ln_g, ln_b, glove, Wk,
                     qh_ws, ql_ws, kh_ws, kl_ws, pk_buf);
  hipLaunchKernelGGL(score_kernel, dim3(5024), dim3(512), 0, stream,
                     qh_ws, ql_ws, kh_ws, kl_ws, pk_buf);
  hipLaunchKernelGGL(out_kernel, dim3(512), dim3(512), 0, stream,
                     queries, glove, Wv, Wout, b_out, pk_buf, out);
}

// Round 18
// 302.570 us; speedup vs baseline: 2.0957x; 1.0067x over previous
//
#include <hip/hip_runtime.h>
#include <cstdint>
#include <cmath>

#define NB 4
#define NQn 128
#define QD 512
#define EMBD 512
#define NH 8
#define DHn 64
#define VOCAB 20000
#define WDn 300
#define VCHUNK 128
#define NCHUNK 157   // ceil(20000/128)

typedef float f32x4 __attribute__((ext_vector_type(4)));
typedef short bf16x8 __attribute__((ext_vector_type(8)));

__device__ __forceinline__ uint32_t rotl(uint32_t x, int r) {
  return __builtin_amdgcn_alignbit(x, x, 32 - r);
}

__device__ __forceinline__ uint32_t cvt_pk_bf16(float a, float b) {
  uint32_t r;
  asm("v_cvt_pk_bf16_f32 %0, %1, %2" : "=v"(r) : "v"(a), "v"(b));
  return r;
}

// split f32x4 -> bf16 hi (RNE) + bf16 residual (verified R12/R13)
__device__ __forceinline__ void split4(f32x4 v, uint2 &hi, uint2 &lo) {
  uint32_t h01 = cvt_pk_bf16(v.x, v.y);
  uint32_t h23 = cvt_pk_bf16(v.z, v.w);
  float rx = v.x - __uint_as_float(h01 << 16);
  float ry = v.y - __uint_as_float(h01 & 0xFFFF0000u);
  float rz = v.z - __uint_as_float(h23 << 16);
  float rw = v.w - __uint_as_float(h23 & 0xFFFF0000u);
  hi = make_uint2(h01, h23);
  lo = make_uint2(cvt_pk_bf16(rx, ry), cvt_pk_bf16(rz, rw));
}

// 8 interleaved threefry2x32 chains (key=(0,42)); bits = out0 ^ out1 (verified R1)
#define TFK1 42u
#define TFK2 (0x1BD11BDAu ^ 42u)
__device__ __forceinline__ void tf8(uint32_t (&x0)[8], uint32_t (&x1)[8]) {
#define R8(r) \
  { _Pragma("unroll") for (int j = 0; j < 8; ++j) { x0[j] += x1[j]; x1[j] = rotl(x1[j], r); x1[j] ^= x0[j]; } }
#define K8(a, b) \
  { _Pragma("unroll") for (int j = 0; j < 8; ++j) { x0[j] += (a); x1[j] += (b); } }
  K8(0u, TFK1)
  R8(13) R8(15) R8(26) R8(6)  K8(TFK1, TFK2 + 1u)
  R8(17) R8(29) R8(16) R8(24) K8(TFK2, 0u + 2u)
  R8(13) R8(15) R8(26) R8(6)  K8(0u, TFK1 + 3u)
  R8(17) R8(29) R8(16) R8(24) K8(TFK1, TFK2 + 4u)
  R8(13) R8(15) R8(26) R8(6)  K8(TFK2, 0u + 5u)
#undef R8
#undef K8
}

// order-isomorphic u64 key: higher val wins; on equal val, LOWER idx wins
__device__ __forceinline__ unsigned long long pack_key(float val, int idx) {
  uint32_t fb = __float_as_uint(val);
  uint32_t key = (fb & 0x80000000u) ? ~fb : (fb | 0x80000000u);
  return ((unsigned long long)key << 32) |
         (unsigned long long)(0xFFFFFFFFu - (uint32_t)idx);
}

// ---------------- K1 (fused): kproj(MFMA) | ln_qproj | pk_buf zero ----------------
// block ids: [0,2560) kproj (XCD-grouped decode), [2560,2816) lnq, 2816 zero.
__global__ __launch_bounds__(256, 4) void prep_kernel(
                             const float* __restrict__ queries,
                             const float* __restrict__ Wq,
                             const float* __restrict__ ln_g,
                             const float* __restrict__ ln_b,
                             const float* __restrict__ glove,
                             const float* __restrict__ Wk,
                             ushort* __restrict__ qh_ws,
                             ushort* __restrict__ ql_ws,
                             ushort* __restrict__ kh_ws,
                             ushort* __restrict__ kl_ws,
                             unsigned long long* __restrict__ pk_buf) {
  __shared__ __align__(16) char smem[32768];
  const int bid = blockIdx.x;
  const int tid = threadIdx.x;

  if (bid < 2560) {
    // ---- kproj via split-bf16 MFMA: k = glove @ Wk -> split bf16 hi/lo ----
    const int lo = bid & 7, h = (bid >> 3) & 7, vg = (bid >> 6) * 8 + lo;
    if (vg >= 313) return;
    const int v0 = vg * 64;
    const int n0 = h * 64;
    char* const Gh = smem;            // [64 rows][64 k]bf16, swizzled, 8 KB
    char* const Gl = smem + 8192;
    char* const Wh = smem + 16384;    // [64 cols][64 k]bf16, swizzled, 8 KB
    char* const Wl = smem + 24576;
    const int w = tid >> 6, lane = tid & 63;
    const int txl = lane & 15;
    const int g4 = (lane >> 4) & 3;
    const int swzA = (txl & 7) << 4;

    f32x4 acc[4] = {};

    for (int s = 0; s < 5; ++s) {
      const int k0 = s * 64;
      __syncthreads();
      for (int f = tid; f < 64 * 16; f += 256) {
        int row = f >> 4, c4 = f & 15;
        int v = v0 + row, kk = k0 + c4 * 4;
        f32x4 g = {0.f, 0.f, 0.f, 0.f};
        if (v < VOCAB && kk + 4 <= WDn)
          g = *(const f32x4*)&glove[(size_t)v * WDn + kk];
        uint2 hi, lov;
        split4(g, hi, lov);
        int off = (row * 128 + c4 * 8) ^ ((row & 7) << 4);
        *(uint2*)(Gh + off) = hi;
        *(uint2*)(Gl + off) = lov;
      }
      for (int f = tid; f < 64 * 16; f += 256) {
        int kk = f >> 4, d4 = f & 15;
        int kg = k0 + kk;
        f32x4 wv = {0.f, 0.f, 0.f, 0.f};
        if (kg < WDn)
          wv = *(const f32x4*)&Wk[(size_t)kg * EMBD + n0 + d4 * 4];
        uint2 hi, lov;
        split4(wv, hi, lov);
        ushort hs[4] = {(ushort)(hi.x & 0xFFFFu), (ushort)(hi.x >> 16),
                        (ushort)(hi.y & 0xFFFFu), (ushort)(hi.y >> 16)};
        ushort ls[4] = {(ushort)(lov.x & 0xFFFFu), (ushort)(lov.x >> 16),
                        (ushort)(lov.y & 0xFFFFu), (ushort)(lov.y >> 16)};
#pragma unroll
        for (int j = 0; j < 4; ++j) {
          int d = d4 * 4 + j;
          int off = (d * 128 + kk * 2) ^ ((d & 7) << 4);
          *(ushort*)(Wh + off) = hs[j];
          *(ushort*)(Wl + off) = ls[j];
        }
      }
      __syncthreads();

      bf16x8 aH[2], aL[2];
#pragma unroll
      for (int kh = 0; kh < 2; ++kh) {
        int off = ((w * 16 + txl) * 128 + (g4 * 8 + kh * 32) * 2) ^ swzA;
        aH[kh] = *(const bf16x8*)(Gh + off);
        aL[kh] = *(const bf16x8*)(Gl + off);
      }
#pragma unroll
      for (int ct = 0; ct < 4; ++ct) {
        bf16x8 bH[2], bL[2];
#pragma unroll
        for (int kh = 0; kh < 2; ++kh) {
          int off = ((ct * 16 + txl) * 128 + (g4 * 8 + kh * 32) * 2) ^ swzA;
          bH[kh] = *(const bf16x8*)(Wh + off);
          bL[kh] = *(const bf16x8*)(Wl + off);
        }
        acc[ct] = __builtin_amdgcn_mfma_f32_16x16x32_bf16(aH[0], bH[0], acc[ct], 0, 0, 0);
        acc[ct] = __builtin_amdgcn_mfma_f32_16x16x32_bf16(aH[1], bH[1], acc[ct], 0, 0, 0);
        acc[ct] = __builtin_amdgcn_mfma_f32_16x16x32_bf16(aH[0], bL[0], acc[ct], 0, 0, 0);
        acc[ct] = __builtin_amdgcn_mfma_f32_16x16x32_bf16(aH[1], bL[1], acc[ct], 0, 0, 0);
        acc[ct] = __builtin_amdgcn_mfma_f32_16x16x32_bf16(aL[0], bH[0], acc[ct], 0, 0, 0);
        acc[ct] = __builtin_amdgcn_mfma_f32_16x16x32_bf16(aL[1], bH[1], acc[ct], 0, 0, 0);
        acc[ct] = __builtin_amdgcn_mfma_f32_16x16x32_bf16(aL[0], bL[0], acc[ct], 0, 0, 0);
        acc[ct] = __builtin_amdgcn_mfma_f32_16x16x32_bf16(aL[1], bL[1], acc[ct], 0, 0, 0);
      }
    }

#pragma unroll
    for (int ct = 0; ct < 4; ++ct) {
#pragma unroll
      for (int i = 0; i < 4; ++i) {
        int v = v0 + w * 16 + (lane >> 4) * 4 + i;
        if (v < VOCAB) {
          float x = acc[ct][i];
          uint32_t hp = cvt_pk_bf16(x, x);
          float resid = x - __uint_as_float(hp << 16);
          uint32_t lp = cvt_pk_bf16(resid, resid);
          size_t off = ((size_t)h * VOCAB + v) * 64 + ct * 16 + txl;
          kh_ws[off] = (ushort)(hp & 0xFFFFu);
          kl_ws[off] = (ushort)(lp & 0xFFFFu);
        }
      }
    }
  } else if (bid < 2816) {
    // ---- ln_qproj -> split bf16 of q*0.125 ----
    const int id = bid - 2560;
    const int bx = id & 127, by = id >> 7;
    float (*xnT)[4] = (float(*)[4])smem;
    const int wave = tid >> 6, lane = tid & 63;
    const int r0 = bx * 4;
    const int r = r0 + wave;

    float vals[8];
    float s = 0.f;
#pragma unroll
    for (int j = 0; j < 8; ++j) { vals[j] = queries[r * QD + j * 64 + lane]; s += vals[j]; }
#pragma unroll
    for (int m = 32; m >= 1; m >>= 1) s += __shfl_xor(s, m, 64);
    const float mu = s * (1.f / 512.f);
    float ss = 0.f;
#pragma unroll
    for (int j = 0; j < 8; ++j) { float d = vals[j] - mu; ss += d * d; }
#pragma unroll
    for (int m = 32; m >= 1; m >>= 1) ss += __shfl_xor(ss, m, 64);
    const float rstd = 1.f / sqrtf(ss * (1.f / 512.f) + 1e-5f);
#pragma unroll
    for (int j = 0; j < 8; ++j) {
      int e = j * 64 + lane;
      xnT[e][wave] = (vals[j] - mu) * rstd * ln_g[e] + ln_b[e];
    }
    __syncthreads();

    const int e = by * 256 + tid;
    float a0 = 0.f, a1 = 0.f, a2 = 0.f, a3 = 0.f;
#pragma unroll 4
    for (int i = 0; i < QD; ++i) {
      f32x4 xv = *(const f32x4*)&xnT[i][0];
      float w = Wq[i * EMBD + e];
      a0 += xv.x * w; a1 += xv.y * w; a2 += xv.z * w; a3 += xv.w * w;
    }
    const int h = e >> 6, d = e & 63;
    float aa[4] = {a0, a1, a2, a3};
#pragma unroll
    for (int i = 0; i < 4; ++i) {
      float q = aa[i] * 0.125f;
      uint32_t hp = cvt_pk_bf16(q, q);
      float resid = q - __uint_as_float(hp << 16);
      uint32_t lp = cvt_pk_bf16(resid, resid);
      size_t off = ((size_t)h * 512 + (r0 + i)) * 64 + d;
      qh_ws[off] = (ushort)(hp & 0xFFFFu);
      ql_ws[off] = (ushort)(lp & 0xFFFFu);
    }
  } else {
    for (int f = tid; f < NB * NH * NQn; f += 256) pk_buf[f] = 0ull;
  }
}

// ---------------- K3: MFMA split-bf16 scores; 256 rows x 128 cols, 16 waves ----------------
template<bool FULL>
__device__ __forceinline__ void score_epi(const f32x4 (&acc)[8],
                                          int v0, int tx, int ty, int rowtile, int h,
                                          unsigned long long* __restrict__ pk_buf) {
#pragma unroll
  for (int i = 0; i < 4; ++i) {
    const int r = rowtile * 256 + ty * 4 + i;    // == rowtile*256 + w*16 + (lane>>4)*4 + i
    const int b = r >> 7, q = r & 127;
    const int rowidx = (b * NH + h) * NQn + q;
    const uint32_t base = (uint32_t)rowidx * (uint32_t)VOCAB;

    uint32_t x0[8], x1[8];
#pragma unroll
    for (int j = 0; j < 8; ++j) {
      x0[j] = 0u;
      x1[j] = base + (uint32_t)(v0 + tx + 16 * j);
    }
    tf8(x0, x1);

    float best = -INFINITY; int bidx = 0x7fffffff;
#pragma unroll
    for (int j = 0; j < 8; ++j) {
      int v = v0 + tx + 16 * j;
      if (FULL || v < VOCAB) {
        uint32_t bits = x0[j] ^ x1[j];
        float f = __uint_as_float((bits >> 9) | 0x3f800000u) - 1.0f;
        float u = fmaxf(f, 1.17549435e-38f);
        float t = __log2f(u);
        float s = __log2f(-t);
        float val = fmaf(-0.69314718f, s, acc[j][i]);   // uniform const dropped
        if (val > best) { best = val; bidx = v; }
      }
    }
#pragma unroll
    for (int m = 8; m >= 1; m >>= 1) {
      float ov = __shfl_xor(best, m, 64);
      int   oi = __shfl_xor(bidx, m, 64);
      if (ov > best || (ov == best && oi < bidx)) { best = ov; bidx = oi; }
    }
    if (tx == 0) atomicMax(&pk_buf[rowidx], pack_key(best, bidx));
  }
}

// 256 rows x 128 cols per block, 1024 threads (16 waves) -> 2 blocks/CU = 32 waves (cap).
// id decode: head=id&7, rowtile=(id>>3)&1, chunk=id>>4; grid 157*16=2512.
__global__ __launch_bounds__(1024, 8) void score_kernel(
                  const ushort* __restrict__ qh_ws,
                  const ushort* __restrict__ ql_ws,
                  const ushort* __restrict__ kh_ws,
                  const ushort* __restrict__ kl_ws,
                  unsigned long long* __restrict__ pk_buf) {
  __shared__ uint4 lds4[2048];         // 32 KB
  char* const Kh = (char*)lds4;
  char* const Kl = Kh + 16384;
  const int tid = threadIdx.x;
  const int id = blockIdx.x;
  const int h = id & 7, rowtile = (id >> 3) & 1, chunk = id >> 4;
  const int v0 = chunk * VCHUNK;
  const int tx = tid & 15, ty = tid >> 4;
  const int w = tid >> 6;              // wave id [0,16)
  const int g4 = (tid >> 4) & 3;
  const int swz = (tx & 7) << 4;

  // stage K tile (swizzled ds_write): 1024 threads cover 128*8 exactly once
  {
    int f = tid;
    int row = f >> 3, c8 = f & 7;
    int v = v0 + row;
    uint4 vh = {0u, 0u, 0u, 0u}, vl = {0u, 0u, 0u, 0u};
    if (v < VOCAB) {
      size_t off = ((size_t)h * VOCAB + v) * 64 + c8 * 8;
      vh = *(const uint4*)(kh_ws + off);
      vl = *(const uint4*)(kl_ws + off);
    }
    int loff = (row * 128 + c8 * 16) ^ ((row & 7) << 4);
    *(uint4*)(Kh + loff) = vh;
    *(uint4*)(Kl + loff) = vl;
  }

  // A fragments from global (private per lane)
  bf16x8 aH[2], aL[2];
  {
    const size_t qbase = ((size_t)h * 512 + rowtile * 256 + w * 16 + tx) * 64 + g4 * 8;
#pragma unroll
    for (int kh = 0; kh < 2; ++kh) {
      aH[kh] = *(const bf16x8*)(qh_ws + qbase + kh * 32);
      aL[kh] = *(const bf16x8*)(ql_ws + qbase + kh * 32);
    }
  }
  __syncthreads();

  f32x4 acc[8] = {};
#pragma unroll
  for (int ct = 0; ct < 8; ++ct) {
    const int bbase = (ct * 16 + tx) * 128 + g4 * 16;
    bf16x8 bH[2], bL[2];
#pragma unroll
    for (int kh = 0; kh < 2; ++kh) {
      int off = (bbase + kh * 64) ^ swz;
      bH[kh] = *(const bf16x8*)(Kh + off);
      bL[kh] = *(const bf16x8*)(Kl + off);
    }
    acc[ct] = __builtin_amdgcn_mfma_f32_16x16x32_bf16(aH[0], bH[0], acc[ct], 0, 0, 0);
    acc[ct] = __builtin_amdgcn_mfma_f32_16x16x32_bf16(aH[1], bH[1], acc[ct], 0, 0, 0);
    acc[ct] = __builtin_amdgcn_mfma_f32_16x16x32_bf16(aH[0], bL[0], acc[ct], 0, 0, 0);
    acc[ct] = __builtin_amdgcn_mfma_f32_16x16x32_bf16(aH[1], bL[1], acc[ct], 0, 0, 0);
    acc[ct] = __builtin_amdgcn_mfma_f32_16x16x32_bf16(aL[0], bH[0], acc[ct], 0, 0, 0);
    acc[ct] = __builtin_amdgcn_mfma_f32_16x16x32_bf16(aL[1], bH[1], acc[ct], 0, 0, 0);
    acc[ct] = __builtin_amdgcn_mfma_f32_16x16x32_bf16(aL[0], bL[0], acc[ct], 0, 0, 0);
    acc[ct] = __builtin_amdgcn_mfma_f32_16x16x32_bf16(aL[1], bL[1], acc[ct], 0, 0, 0);
  }

  if (v0 + VCHUNK <= VOCAB)
    score_epi<true>(acc, v0, tx, ty, rowtile, h, pk_buf);
  else
    score_epi<false>(acc, v0, tx, ty, rowtile, h, pk_buf);
}

// ---------------- K5: gather + V proj + out proj + residual (R15 verbatim) ----------------
__global__ __launch_bounds__(512, 8) void out_kernel(
                           const float* __restrict__ queries,
                           const float* __restrict__ glove,
                           const float* __restrict__ Wv,
                           const float* __restrict__ Wout,
                           const float* __restrict__ b_out,
                           const unsigned long long* __restrict__ pk_buf,
                           float* __restrict__ out) {
  __shared__ float gl[NH][WDn];
  __shared__ float vrow[EMBD];
  __shared__ int idxs[NH];
  const int tid = threadIdx.x;
  const int r = blockIdx.x, b = r >> 7, q = r & 127;
  if (tid < NH) {
    unsigned long long p = pk_buf[(b * NH + tid) * NQn + q];
    idxs[tid] = (int)(0xFFFFFFFFu - (uint32_t)(p & 0xFFFFFFFFull));
  }
  __syncthreads();
  for (int f = tid; f < NH * 75; f += 512) {
    int hh = f / 75, c4 = f % 75;
    *(float4*)&gl[hh][c4 * 4] = *(const float4*)&glove[(size_t)idxs[hh] * WDn + c4 * 4];
  }
  __syncthreads();
  {
    const int e = tid, hh = e >> 6;
    float a = 0.f;
    for (int w = 0; w < WDn; ++w) a += gl[hh][w] * Wv[(size_t)w * EMBD + e];
    vrow[e] = a;
  }
  __syncthreads();
  {
    const int j = tid;
    float o = 0.f;
    for (int e = 0; e < EMBD; ++e) o += vrow[e] * Wout[(size_t)e * QD + j];
    out[(size_t)r * QD + j] = queries[(size_t)r * QD + j] + o + b_out[j];
  }
}

extern "C" void kernel_launch(void* const* d_in, const int* in_sizes, int n_in,
                              void* d_out, int out_size, void* d_ws, size_t ws_size,
                              hipStream_t stream) {
  const float* queries = (const float*)d_in[0];
  const float* glove   = (const float*)d_in[1];
  const float* Wq      = (const float*)d_in[2];
  const float* Wk      = (const float*)d_in[3];
  const float* Wv      = (const float*)d_in[4];
  const float* Wout    = (const float*)d_in[5];
  const float* b_out   = (const float*)d_in[6];
  const float* ln_g    = (const float*)d_in[7];
  const float* ln_b    = (const float*)d_in[8];
  float* out = (float*)d_out;

  // ws layout: qh | ql | kh | kl | pk_buf
  char* ws = (char*)d_ws;
  ushort* qh_ws = (ushort*)ws;
  ushort* ql_ws = qh_ws + (size_t)NH * 512 * 64;
  ushort* kh_ws = ql_ws + (size_t)NH * 512 * 64;
  ushort* kl_ws = kh_ws + (size_t)NH * VOCAB * 64;
  unsigned long long* pk_buf = (unsigned long long*)(kl_ws + (size_t)NH * VOCAB * 64);

  hipLaunchKernelGGL(prep_kernel, dim3(2817), dim3(256), 0, stream,
                     queries, Wq, ln_g, ln_b, glove, Wk,
                     qh_ws, ql_ws, kh_ws, kl_ws, pk_buf);
  hipLaunchKernelGGL(score_kernel, dim3(2512), dim3(1024), 0, stream,
                     qh_ws, ql_ws, kh_ws, kl_ws, pk_buf);
  hipLaunchKernelGGL(out_kernel, dim3(512), dim3(512), 0, stream,
                     queries, glove, Wv, Wout, b_out, pk_buf, out);
}